// Round 1
// baseline (3325.231 us; speedup 1.0000x reference)
//
#include <hip/hip_runtime.h>

#define UU 60000
#define II 90000
#define DD 64
#define NN 150000
#define NNZC 1000000

// ws layout (floats):
//   chanEmb : 5*NN*DD   = 48,000,000   (rating channel mean embeddings; social reuses this after mixes)
//   Bbuf    : NN*DD     =  9,600,000   (spmm temp; later mixed_rating_user)
//   wrat    : 5*NN      =    750,000   (attention logits per channel)
//   vvec    : 3*64      =        192   (precomputed M^T a for user/item/social)
// total = 58,350,192 floats = 233,400,768 bytes

__device__ __forceinline__ float wave_sum(float x) {
#pragma unroll
    for (int m = 32; m >= 1; m >>= 1) x += __shfl_xor(x, m, 64);
    return x;
}

__global__ void att_vec_kernel(const float* __restrict__ au, const float* __restrict__ Mu,
                               const float* __restrict__ ai, const float* __restrict__ Mi,
                               const float* __restrict__ as_, const float* __restrict__ Ms,
                               float* __restrict__ v) {
    int d = threadIdx.x;  // 64 threads
    float su = 0.f, si = 0.f, ss = 0.f;
    for (int e = 0; e < DD; ++e) {
        su += au[e] * Mu[e * DD + d];
        si += ai[e] * Mi[e * DD + d];
        ss += as_[e] * Ms[e * DD + d];
    }
    v[d] = su;
    v[DD + d] = si;
    v[2 * DD + d] = ss;
}

// out[rows[e]] += vals[e] * x[cols[e]]; x is split across xlo (idx < split) / xhi.
// One wave per edge iteration; lane = feature dim.
__global__ void spmm_kernel(const int* __restrict__ rows, const int* __restrict__ cols,
                            const float* __restrict__ vals, int nnz,
                            const float* __restrict__ xlo, const float* __restrict__ xhi,
                            int split, float* __restrict__ out) {
    int lane = threadIdx.x & 63;
    int gw = blockIdx.x * (blockDim.x >> 6) + (threadIdx.x >> 6);
    int nw = gridDim.x * (blockDim.x >> 6);
    for (int e = gw; e < nnz; e += nw) {
        int r = rows[e];
        int c = cols[e];
        float v = vals[e];
        const float* src = (c < split) ? (xlo + (size_t)c * DD) : (xhi + (size_t)(c - split) * DD);
        __hip_atomic_fetch_add(&out[(size_t)r * DD + lane], v * src[lane],
                               __ATOMIC_RELAXED, __HIP_MEMORY_SCOPE_AGENT);
    }
}

// A = (A + B) / 2 ; w[row] = tanh(dot(A_row, v)) with v = v_user (row<UU) else v_item
__global__ void mean_w_kernel(float* __restrict__ A, const float* __restrict__ B,
                              const float* __restrict__ vu, const float* __restrict__ vi,
                              float* __restrict__ w) {
    int lane = threadIdx.x & 63;
    int row = blockIdx.x * (blockDim.x >> 6) + (threadIdx.x >> 6);
    if (row >= NN) return;
    size_t idx = (size_t)row * DD + lane;
    float m = (A[idx] + B[idx]) * 0.5f;
    A[idx] = m;
    float v = (row < UU) ? vu[lane] : vi[lane];
    float s = wave_sum(m * v);
    if (lane == 0) w[row] = tanhf(s);
}

// softmax over 5 channels per row; write scores + mixed embedding
__global__ void mix5_kernel(const float* __restrict__ chanEmb, const float* __restrict__ w,
                            int rowOff, int nRows, int scoreStride,
                            float* __restrict__ scoresOut, float* __restrict__ mixedOut) {
    int lane = threadIdx.x & 63;
    int n = blockIdx.x * (blockDim.x >> 6) + (threadIdx.x >> 6);
    if (n >= nRows) return;
    int gn = n + rowOff;
    float sw[5];
    float mx = -2.0f;
#pragma unroll
    for (int c = 0; c < 5; ++c) {
        sw[c] = w[(size_t)c * NN + gn];
        mx = fmaxf(mx, sw[c]);
    }
    float sum = 0.f;
#pragma unroll
    for (int c = 0; c < 5; ++c) {
        sw[c] = expf(sw[c] - mx);
        sum += sw[c];
    }
    float inv = 1.0f / sum;
    float acc = 0.f;
#pragma unroll
    for (int c = 0; c < 5; ++c) {
        float s = sw[c] * inv;
        if (lane == c) scoresOut[(size_t)c * scoreStride + n] = s;
        acc += s * chanEmb[((size_t)c * NN + gn) * DD + lane];
    }
    mixedOut[(size_t)n * DD + lane] = acc;
}

__global__ void l2norm_kernel(float* __restrict__ x, int nRows) {
    int lane = threadIdx.x & 63;
    int n = blockIdx.x * (blockDim.x >> 6) + (threadIdx.x >> 6);
    if (n >= nRows) return;
    size_t idx = (size_t)n * DD + lane;
    float v = x[idx];
    float s = wave_sum(v * v);
    float nrm = sqrtf(s);
    x[idx] = v / fmaxf(nrm, 1e-12f);
}

__global__ void avg_kernel(float* __restrict__ a, const float* __restrict__ b, int n) {
    int i = blockIdx.x * blockDim.x + threadIdx.x;
    if (i < n) a[i] = (a[i] + b[i]) * 0.5f;
}

// 2-channel softmax fuse for social embeddings
__global__ void social_mix_kernel(const float* __restrict__ e0, const float* __restrict__ e1,
                                  const float* __restrict__ vs,
                                  float* __restrict__ scoresOut, float* __restrict__ mixedOut) {
    int lane = threadIdx.x & 63;
    int n = blockIdx.x * (blockDim.x >> 6) + (threadIdx.x >> 6);
    if (n >= UU) return;
    size_t idx = (size_t)n * DD + lane;
    float a = e0[idx];
    float b = e1[idx];
    float v = vs[lane];
    float w0 = tanhf(wave_sum(a * v));
    float w1 = tanhf(wave_sum(b * v));
    float mx = fmaxf(w0, w1);
    float x0 = expf(w0 - mx);
    float x1 = expf(w1 - mx);
    float inv = 1.0f / (x0 + x1);
    float s0 = x0 * inv;
    float s1 = x1 * inv;
    if (lane == 0) {
        scoresOut[n] = s0;
        scoresOut[UU + n] = s1;
    }
    mixedOut[idx] = s0 * a + s1 * b;
}

__global__ void final_kernel(const float* __restrict__ mru, const float* __restrict__ msoc,
                             const float* __restrict__ adaptive, float* __restrict__ outMU) {
    int lane = threadIdx.x & 63;
    int n = blockIdx.x * (blockDim.x >> 6) + (threadIdx.x >> 6);
    if (n >= UU) return;
    size_t idx = (size_t)n * DD + lane;
    float a = mru[idx];
    float b = msoc[idx];
    float num = wave_sum(a * b);
    float na = sqrtf(wave_sum(a * a));
    float nb = sqrtf(wave_sum(b * b));
    float denom = fmaxf(na, 1e-8f) * fmaxf(nb, 1e-8f);
    float sim = num / denom;
    float up0 = fmaxf(sim, 0.f);
    float rate = 1.0f / (2.0f + up0 * adaptive[n]);  // EMB_COMB / (base + ...)
    outMU[idx] = a + b * rate;
}

extern "C" void kernel_launch(void* const* d_in, const int* in_sizes, int n_in,
                              void* d_out, int out_size, void* d_ws, size_t ws_size,
                              hipStream_t stream) {
    const int* r_rows = (const int*)d_in[0];
    const int* r_cols = (const int*)d_in[1];
    const float* r_vals = (const float*)d_in[2];
    const int* f_rows = (const int*)d_in[3];
    const int* f_cols = (const int*)d_in[4];
    const float* f_vals = (const float*)d_in[5];
    const int* g_rows = (const int*)d_in[6];
    const int* g_cols = (const int*)d_in[7];
    const float* g_vals = (const float*)d_in[8];
    const float* rue = (const float*)d_in[9];
    const float* rie = (const float*)d_in[10];
    const float* femb = (const float*)d_in[11];
    const float* gemb = (const float*)d_in[12];
    const float* uaw = (const float*)d_in[13];
    const float* uamw = (const float*)d_in[14];
    const float* iaw = (const float*)d_in[15];
    const float* iamw = (const float*)d_in[16];
    const float* saw = (const float*)d_in[17];
    const float* samw = (const float*)d_in[18];
    const float* adapt = (const float*)d_in[19];

    float* ws = (float*)d_ws;
    float* chanEmb = ws;
    float* Bbuf = chanEmb + (size_t)5 * NN * DD;
    float* wrat = Bbuf + (size_t)NN * DD;
    float* vvec = wrat + (size_t)5 * NN;

    // social-phase aliases (chanEmb region is dead after the two mix5 launches)
    float* soc0 = chanEmb;
    float* soc1 = chanEmb + (size_t)UU * DD;
    float* soct = chanEmb + (size_t)2 * UU * DD;
    float* mixedSoc = chanEmb + (size_t)3 * UU * DD;
    float* mixedRU = Bbuf;  // Bbuf dead after last mean_w

    float* out = (float*)d_out;
    float* oUS = out;                              // [5, UU]
    float* oIS = oUS + (size_t)5 * UU;             // [5, II]
    float* oSS = oIS + (size_t)5 * II;             // [2, UU]
    float* oMU = oSS + (size_t)2 * UU;             // [UU, DD]
    float* oMI = oMU + (size_t)UU * DD;            // [II, DD]

    const dim3 blk(256);
    const int gridN = (NN + 3) / 4;   // 4 waves/block
    const int gridU = (UU + 3) / 4;
    const int gridI = (II + 3) / 4;
    const int gridSp = 8192;
    const int gridAvg = (UU * DD + 255) / 256;

    att_vec_kernel<<<1, 64, 0, stream>>>(uaw, uamw, iaw, iamw, saw, samw, vvec);

    // ---- rating channels ----
    for (int c = 0; c < 5; ++c) {
        float* A = chanEmb + (size_t)c * NN * DD;
        hipMemsetAsync(A, 0, (size_t)NN * DD * sizeof(float), stream);
        spmm_kernel<<<gridSp, blk, 0, stream>>>(r_rows + (size_t)c * NNZC, r_cols + (size_t)c * NNZC,
                                                r_vals + (size_t)c * NNZC, NNZC,
                                                rue + (size_t)c * UU * DD, rie + (size_t)c * II * DD,
                                                UU, A);
        hipMemsetAsync(Bbuf, 0, (size_t)NN * DD * sizeof(float), stream);
        spmm_kernel<<<gridSp, blk, 0, stream>>>(r_rows + (size_t)c * NNZC, r_cols + (size_t)c * NNZC,
                                                r_vals + (size_t)c * NNZC, NNZC,
                                                A, A, NN, Bbuf);
        mean_w_kernel<<<gridN, blk, 0, stream>>>(A, Bbuf, vvec, vvec + DD, wrat + (size_t)c * NN);
    }

    // ---- attention fuse (rating) ----
    mix5_kernel<<<gridU, blk, 0, stream>>>(chanEmb, wrat, 0, UU, UU, oUS, mixedRU);
    mix5_kernel<<<gridI, blk, 0, stream>>>(chanEmb, wrat, UU, II, II, oIS, oMI);

    // ---- social: friend ----
    hipMemsetAsync(soc0, 0, (size_t)UU * DD * sizeof(float), stream);
    spmm_kernel<<<gridSp, blk, 0, stream>>>(f_rows, f_cols, f_vals, NNZC, femb, femb, UU, soc0);
    l2norm_kernel<<<gridU, blk, 0, stream>>>(soc0, UU);
    hipMemsetAsync(soct, 0, (size_t)UU * DD * sizeof(float), stream);
    spmm_kernel<<<gridSp, blk, 0, stream>>>(f_rows, f_cols, f_vals, NNZC, soc0, soc0, UU, soct);
    l2norm_kernel<<<gridU, blk, 0, stream>>>(soct, UU);
    avg_kernel<<<gridAvg, blk, 0, stream>>>(soc0, soct, UU * DD);

    // ---- social: group ----
    hipMemsetAsync(soc1, 0, (size_t)UU * DD * sizeof(float), stream);
    spmm_kernel<<<gridSp, blk, 0, stream>>>(g_rows, g_cols, g_vals, NNZC, gemb, gemb, UU, soc1);
    l2norm_kernel<<<gridU, blk, 0, stream>>>(soc1, UU);
    hipMemsetAsync(soct, 0, (size_t)UU * DD * sizeof(float), stream);
    spmm_kernel<<<gridSp, blk, 0, stream>>>(g_rows, g_cols, g_vals, NNZC, soc1, soc1, UU, soct);
    l2norm_kernel<<<gridU, blk, 0, stream>>>(soct, UU);
    avg_kernel<<<gridAvg, blk, 0, stream>>>(soc1, soct, UU * DD);

    // ---- social fuse + adaptive combine ----
    social_mix_kernel<<<gridU, blk, 0, stream>>>(soc0, soc1, vvec + 2 * DD, oSS, mixedSoc);
    final_kernel<<<gridU, blk, 0, stream>>>(mixedRU, mixedSoc, adapt, oMU);
}

// Round 2
// 2057.368 us; speedup vs baseline: 1.6163x; 1.6163x over previous
//
#include <hip/hip_runtime.h>
#include <hip/hip_bf16.h>

#define UU 60000
#define II 90000
#define DD 64
#define NN 150000
#define NNZC 1000000
#define NGRAPH 7
#define MTOT (5 * NN + 2 * UU)   // 870,000 concatenated degree slots
#define SCAN_CHUNK 2048
#define NPART ((MTOT + SCAN_CHUNK - 1) / SCAN_CHUNK)  // 425

// ws layout (float units):
//   rowptr  : int[MTOT]            -> 870,016
//   partials: int[2048]
//   edata   : uint2[7M]            -> 14,000,000 floats
//   Atmp    : f32[NN*DD]           ->  9,600,000   (rating L1 out; later mixedRU)
//   chanMean: bf16[5*NN*DD]        -> 24,000,000 floats  (social temps alias here)
//   wrat    : f32[5*NN]            ->    750,016
//   vvec    : f32[192]
// total ~ 49.2M floats ~ 197 MB

__device__ __forceinline__ float wave_sum(float x) {
#pragma unroll
    for (int m = 32; m >= 1; m >>= 1) x += __shfl_xor(x, m, 64);
    return x;
}

__device__ __forceinline__ int wave_incl_scan(int x) {
    int lane = threadIdx.x & 63;
#pragma unroll
    for (int d = 1; d < 64; d <<= 1) {
        int y = __shfl_up(x, d, 64);
        if (lane >= d) x += y;
    }
    return x;
}

// 256-thread block inclusive scan; lds must be int[8] shared
__device__ int block_incl_scan(int x, int* lds) {
    int wid = threadIdx.x >> 6, lane = threadIdx.x & 63;
    int ws_ = wave_incl_scan(x);
    if (lane == 63) lds[wid] = ws_;
    __syncthreads();
    int off = 0;
    for (int w = 0; w < wid; ++w) off += lds[w];
    __syncthreads();
    return ws_ + off;
}

__global__ void att_vec_kernel(const float* __restrict__ au, const float* __restrict__ Mu,
                               const float* __restrict__ ai, const float* __restrict__ Mi,
                               const float* __restrict__ as_, const float* __restrict__ Ms,
                               float* __restrict__ v) {
    int d = threadIdx.x;  // 64 threads
    float su = 0.f, si = 0.f, ss = 0.f;
    for (int e = 0; e < DD; ++e) {
        su += au[e] * Mu[e * DD + d];
        si += ai[e] * Mi[e * DD + d];
        ss += as_[e] * Ms[e * DD + d];
    }
    v[d] = su;
    v[DD + d] = si;
    v[2 * DD + d] = ss;
}

__global__ void hist_kernel(const int* __restrict__ rR, const int* __restrict__ fR,
                            const int* __restrict__ gR, int* __restrict__ deg) {
    const int nTot = NGRAPH * NNZC;
    for (int e = blockIdx.x * blockDim.x + threadIdx.x; e < nTot; e += gridDim.x * blockDim.x) {
        int r, bg;
        if (e < 5 * NNZC) { r = rR[e]; bg = (e / NNZC) * NN; }
        else if (e < 6 * NNZC) { r = fR[e - 5 * NNZC]; bg = 5 * NN; }
        else { r = gR[e - 6 * NNZC]; bg = 5 * NN + UU; }
        atomicAdd(&deg[bg + r], 1);
    }
}

__global__ void scanA_kernel(const int* __restrict__ deg, int* __restrict__ partials) {
    __shared__ int lds[8];
    int base = blockIdx.x * SCAN_CHUNK + threadIdx.x * 8;
    int s = 0;
#pragma unroll
    for (int k = 0; k < 8; ++k) {
        int i = base + k;
        s += (i < MTOT) ? deg[i] : 0;
    }
    int incl = block_incl_scan(s, lds);
    if (threadIdx.x == 255) partials[blockIdx.x] = incl;
}

__global__ void scanB_kernel(int* __restrict__ partials) {
    __shared__ int lds[8];
    __shared__ int sOff;
    __shared__ int sTot;
    if (threadIdx.x == 0) sOff = 0;
    __syncthreads();
    for (int base = 0; base < NPART; base += 256) {
        int i = base + threadIdx.x;
        int v = (i < NPART) ? partials[i] : 0;
        int incl = block_incl_scan(v, lds);
        if (threadIdx.x == 255) sTot = incl;
        __syncthreads();
        if (i < NPART) partials[i] = sOff + incl - v;
        __syncthreads();
        if (threadIdx.x == 0) sOff += sTot;
        __syncthreads();
    }
}

// in-place exclusive scan of deg -> rowptr (starts)
__global__ void scanC_kernel(int* __restrict__ deg, const int* __restrict__ partials) {
    __shared__ int lds[8];
    int base = blockIdx.x * SCAN_CHUNK + threadIdx.x * 8;
    int v[8];
    int s = 0;
#pragma unroll
    for (int k = 0; k < 8; ++k) {
        int i = base + k;
        v[k] = (i < MTOT) ? deg[i] : 0;
        s += v[k];
    }
    int incl = block_incl_scan(s, lds);
    int run = incl - s + partials[blockIdx.x];
#pragma unroll
    for (int k = 0; k < 8; ++k) {
        int i = base + k;
        if (i < MTOT) deg[i] = run;
        run += v[k];
    }
}

// scatter edges into CSR slots; bumps rowptr[row] start -> end
__global__ void scatter_kernel(const int* __restrict__ rR, const int* __restrict__ rC,
                               const float* __restrict__ rV,
                               const int* __restrict__ fR, const int* __restrict__ fC,
                               const float* __restrict__ fV,
                               const int* __restrict__ gR, const int* __restrict__ gC,
                               const float* __restrict__ gV,
                               int* __restrict__ rowptr, uint2* __restrict__ edata) {
    const int nTot = NGRAPH * NNZC;
    for (int e = blockIdx.x * blockDim.x + threadIdx.x; e < nTot; e += gridDim.x * blockDim.x) {
        int r, c, bg;
        float v;
        if (e < 5 * NNZC) {
            r = rR[e]; c = rC[e]; v = rV[e]; bg = (e / NNZC) * NN;
        } else if (e < 6 * NNZC) {
            int k = e - 5 * NNZC;
            r = fR[k]; c = fC[k]; v = fV[k]; bg = 5 * NN;
        } else {
            int k = e - 6 * NNZC;
            r = gR[k]; c = gC[k]; v = gV[k]; bg = 5 * NN + UU;
        }
        int pos = atomicAdd(&rowptr[bg + r], 1);
        edata[pos] = make_uint2((unsigned)c, __float_as_uint(v));
    }
}

// MODE 0: rating L1  -> outF = acc (split gather from xlo/xhi)
// MODE 1: rating L2  -> m = 0.5*(acc + selfRow[r]); outB = bf16(m); wOut = tanh(dot(m, v))
// MODE 2: social L1  -> outF = l2norm(acc)
// MODE 3: social L2  -> outF = 0.5*(selfRow[r] + l2norm(acc))
template <int MODE>
__global__ void spmm_csr_kernel(const int* __restrict__ rowptr, int rowBase, int edgeBase,
                                const uint2* __restrict__ edata,
                                const float* __restrict__ xlo, const float* __restrict__ xhi,
                                int split,
                                const float* __restrict__ selfRow,
                                const float* __restrict__ vvec,
                                float* __restrict__ outF,
                                __hip_bfloat16* __restrict__ outB,
                                float* __restrict__ wOut, int nRows) {
    int lane = threadIdx.x & 63;
    int row = blockIdx.x * (blockDim.x >> 6) + (threadIdx.x >> 6);
    if (row >= nRows) return;
    int start = (row == 0) ? edgeBase : rowptr[rowBase + row - 1];
    int end = rowptr[rowBase + row];
    float acc = 0.f;
    for (int j0 = start; j0 < end; j0 += 64) {
        uint2 md = {0u, 0u};
        if (j0 + lane < end) md = edata[j0 + lane];
        int cnt = min(end - j0, 64);
        for (int j = 0; j < cnt; ++j) {
            int c = __shfl((int)md.x, j, 64);
            float v = __uint_as_float((unsigned)__shfl((int)md.y, j, 64));
            const float* src = (c < split) ? (xlo + (size_t)c * DD)
                                           : (xhi + (size_t)(c - split) * DD);
            acc += v * src[lane];
        }
    }
    if (MODE == 0) {
        outF[(size_t)row * DD + lane] = acc;
    } else if (MODE == 1) {
        float m = 0.5f * (acc + selfRow[(size_t)row * DD + lane]);
        outB[(size_t)row * DD + lane] = __float2bfloat16(m);
        const float* v = (row < UU) ? vvec : (vvec + DD);
        float s = wave_sum(m * v[lane]);
        if (lane == 0) wOut[row] = tanhf(s);
    } else if (MODE == 2) {
        float nrm = sqrtf(wave_sum(acc * acc));
        outF[(size_t)row * DD + lane] = acc / fmaxf(nrm, 1e-12f);
    } else {
        float nrm = sqrtf(wave_sum(acc * acc));
        float l2 = acc / fmaxf(nrm, 1e-12f);
        outF[(size_t)row * DD + lane] = 0.5f * (selfRow[(size_t)row * DD + lane] + l2);
    }
}

// softmax over 5 channels per row (bf16 channel embeddings)
__global__ void mix5_kernel(const __hip_bfloat16* __restrict__ chanEmb,
                            const float* __restrict__ w,
                            int rowOff, int nRows, int scoreStride,
                            float* __restrict__ scoresOut, float* __restrict__ mixedOut) {
    int lane = threadIdx.x & 63;
    int n = blockIdx.x * (blockDim.x >> 6) + (threadIdx.x >> 6);
    if (n >= nRows) return;
    int gn = n + rowOff;
    float sw[5];
    float mx = -2.0f;
#pragma unroll
    for (int c = 0; c < 5; ++c) {
        sw[c] = w[(size_t)c * NN + gn];
        mx = fmaxf(mx, sw[c]);
    }
    float sum = 0.f;
#pragma unroll
    for (int c = 0; c < 5; ++c) {
        sw[c] = expf(sw[c] - mx);
        sum += sw[c];
    }
    float inv = 1.0f / sum;
    float acc = 0.f;
#pragma unroll
    for (int c = 0; c < 5; ++c) {
        float s = sw[c] * inv;
        if (lane == c) scoresOut[(size_t)c * scoreStride + n] = s;
        acc += s * __bfloat162float(chanEmb[((size_t)c * NN + gn) * DD + lane]);
    }
    mixedOut[(size_t)n * DD + lane] = acc;
}

// social 2-channel softmax fuse + adaptive final combine
__global__ void social_mix_final_kernel(const float* __restrict__ e0, const float* __restrict__ e1,
                                        const float* __restrict__ vs,
                                        const float* __restrict__ mixedRU,
                                        const float* __restrict__ adaptive,
                                        float* __restrict__ scoresOut,
                                        float* __restrict__ outMU) {
    int lane = threadIdx.x & 63;
    int n = blockIdx.x * (blockDim.x >> 6) + (threadIdx.x >> 6);
    if (n >= UU) return;
    size_t idx = (size_t)n * DD + lane;
    float a = e0[idx];
    float b = e1[idx];
    float v = vs[lane];
    float w0 = tanhf(wave_sum(a * v));
    float w1 = tanhf(wave_sum(b * v));
    float mx = fmaxf(w0, w1);
    float x0 = expf(w0 - mx);
    float x1 = expf(w1 - mx);
    float inv = 1.0f / (x0 + x1);
    float s0 = x0 * inv;
    float s1 = x1 * inv;
    if (lane == 0) {
        scoresOut[n] = s0;
        scoresOut[UU + n] = s1;
    }
    float ms = s0 * a + s1 * b;
    float mru = mixedRU[idx];
    float num = wave_sum(mru * ms);
    float na = sqrtf(wave_sum(mru * mru));
    float nb = sqrtf(wave_sum(ms * ms));
    float denom = fmaxf(na, 1e-8f) * fmaxf(nb, 1e-8f);
    float sim = num / denom;
    float rate = 1.0f / (2.0f + fmaxf(sim, 0.f) * adaptive[n]);
    outMU[idx] = mru + ms * rate;
}

extern "C" void kernel_launch(void* const* d_in, const int* in_sizes, int n_in,
                              void* d_out, int out_size, void* d_ws, size_t ws_size,
                              hipStream_t stream) {
    const int* r_rows = (const int*)d_in[0];
    const int* r_cols = (const int*)d_in[1];
    const float* r_vals = (const float*)d_in[2];
    const int* f_rows = (const int*)d_in[3];
    const int* f_cols = (const int*)d_in[4];
    const float* f_vals = (const float*)d_in[5];
    const int* g_rows = (const int*)d_in[6];
    const int* g_cols = (const int*)d_in[7];
    const float* g_vals = (const float*)d_in[8];
    const float* rue = (const float*)d_in[9];
    const float* rie = (const float*)d_in[10];
    const float* femb = (const float*)d_in[11];
    const float* gemb = (const float*)d_in[12];
    const float* uaw = (const float*)d_in[13];
    const float* uamw = (const float*)d_in[14];
    const float* iaw = (const float*)d_in[15];
    const float* iamw = (const float*)d_in[16];
    const float* saw = (const float*)d_in[17];
    const float* samw = (const float*)d_in[18];
    const float* adapt = (const float*)d_in[19];

    float* ws = (float*)d_ws;
    int* rowptr = (int*)ws;                                   // MTOT ints
    int* partials = rowptr + 870016;                          // 2048 ints
    uint2* edata = (uint2*)(ws + 870016 + 2048);              // 7M uint2 = 14M floats
    float* Atmp = ws + 870016 + 2048 + 14000000;              // NN*DD f32
    __hip_bfloat16* chanMean = (__hip_bfloat16*)(Atmp + (size_t)NN * DD);  // 5*NN*DD bf16
    float* wrat = (float*)(chanMean + (size_t)5 * NN * DD);   // 5*NN f32
    float* vvec = wrat + (size_t)5 * NN;                      // 192 f32

    // social temps alias the chanMean region (dead after mix5)
    float* socArea = (float*)chanMean;
    float* socL1 = socArea;                         // UU*DD
    float* socM0 = socL1 + (size_t)UU * DD;         // friend mean
    float* socM1 = socM0 + (size_t)UU * DD;         // group mean
    float* mixedRU = Atmp;                          // Atmp dead after rating loop

    float* out = (float*)d_out;
    float* oUS = out;                               // [5, UU]
    float* oIS = oUS + (size_t)5 * UU;              // [5, II]
    float* oSS = oIS + (size_t)5 * II;              // [2, UU]
    float* oMU = oSS + (size_t)2 * UU;              // [UU, DD]
    float* oMI = oMU + (size_t)UU * DD;             // [II, DD]

    const dim3 blk(256);
    const int gridN = (NN + 3) / 4;
    const int gridU = (UU + 3) / 4;
    const int gridI = (II + 3) / 4;
    const int gridEdge = 4096;

    att_vec_kernel<<<1, 64, 0, stream>>>(uaw, uamw, iaw, iamw, saw, samw, vvec);

    // ---- build CSR for all 7 graphs ----
    hipMemsetAsync(rowptr, 0, MTOT * sizeof(int), stream);
    hist_kernel<<<gridEdge, blk, 0, stream>>>(r_rows, f_rows, g_rows, rowptr);
    scanA_kernel<<<NPART, blk, 0, stream>>>(rowptr, partials);
    scanB_kernel<<<1, blk, 0, stream>>>(partials);
    scanC_kernel<<<NPART, blk, 0, stream>>>(rowptr, partials);
    scatter_kernel<<<gridEdge, blk, 0, stream>>>(r_rows, r_cols, r_vals,
                                                 f_rows, f_cols, f_vals,
                                                 g_rows, g_cols, g_vals, rowptr, edata);

    // ---- rating channels ----
    for (int c = 0; c < 5; ++c) {
        int rb = c * NN;
        int eb = c * NNZC;
        spmm_csr_kernel<0><<<gridN, blk, 0, stream>>>(
            rowptr, rb, eb, edata,
            rue + (size_t)c * UU * DD, rie + (size_t)c * II * DD, UU,
            nullptr, nullptr, Atmp, nullptr, nullptr, NN);
        spmm_csr_kernel<1><<<gridN, blk, 0, stream>>>(
            rowptr, rb, eb, edata,
            Atmp, Atmp, NN,
            Atmp, vvec, nullptr, chanMean + (size_t)c * NN * DD, wrat + (size_t)c * NN, NN);
    }

    // ---- attention fuse (rating) ----
    mix5_kernel<<<gridI, blk, 0, stream>>>(chanMean, wrat, UU, II, II, oIS, oMI);
    mix5_kernel<<<gridU, blk, 0, stream>>>(chanMean, wrat, 0, UU, UU, oUS, mixedRU);

    // ---- social: friend (graph 5) ----
    {
        int rb = 5 * NN, eb = 5 * NNZC;
        spmm_csr_kernel<2><<<gridU, blk, 0, stream>>>(rowptr, rb, eb, edata,
                                                      femb, femb, UU, nullptr, nullptr,
                                                      socL1, nullptr, nullptr, UU);
        spmm_csr_kernel<3><<<gridU, blk, 0, stream>>>(rowptr, rb, eb, edata,
                                                      socL1, socL1, UU, socL1, nullptr,
                                                      socM0, nullptr, nullptr, UU);
    }
    // ---- social: group (graph 6) ----
    {
        int rb = 5 * NN + UU, eb = 6 * NNZC;
        spmm_csr_kernel<2><<<gridU, blk, 0, stream>>>(rowptr, rb, eb, edata,
                                                      gemb, gemb, UU, nullptr, nullptr,
                                                      socL1, nullptr, nullptr, UU);
        spmm_csr_kernel<3><<<gridU, blk, 0, stream>>>(rowptr, rb, eb, edata,
                                                      socL1, socL1, UU, socL1, nullptr,
                                                      socM1, nullptr, nullptr, UU);
    }

    // ---- social fuse + adaptive combine ----
    social_mix_final_kernel<<<gridU, blk, 0, stream>>>(socM0, socM1, vvec + 2 * DD,
                                                       mixedRU, adapt, oSS, oMU);
}

// Round 3
// 1830.522 us; speedup vs baseline: 1.8165x; 1.1239x over previous
//
#include <hip/hip_runtime.h>
#include <hip/hip_bf16.h>

#define UU 60000
#define II 90000
#define DD 64
#define NN 150000
#define NNZC 1000000
#define NGRAPH 7
#define MTOT (5 * NN + 2 * UU)   // 870,000
#define SCAN_CHUNK 2048
#define NPART ((MTOT + SCAN_CHUNK - 1) / SCAN_CHUNK)  // 425
#define NB 256
#define RPB ((MTOT + NB - 1) / NB)   // 3399 rows per bucket
#define ACHUNK 8192                   // edges per phase-A block

__device__ __forceinline__ float wave_sum(float x) {
#pragma unroll
    for (int m = 32; m >= 1; m >>= 1) x += __shfl_xor(x, m, 64);
    return x;
}

__device__ __forceinline__ int wave_incl_scan(int x) {
    int lane = threadIdx.x & 63;
#pragma unroll
    for (int d = 1; d < 64; d <<= 1) {
        int y = __shfl_up(x, d, 64);
        if (lane >= d) x += y;
    }
    return x;
}

__device__ int block_incl_scan(int x, int* lds) {
    int wid = threadIdx.x >> 6, lane = threadIdx.x & 63;
    int ws_ = wave_incl_scan(x);
    if (lane == 63) lds[wid] = ws_;
    __syncthreads();
    int off = 0;
    for (int w = 0; w < wid; ++w) off += lds[w];
    __syncthreads();
    return ws_ + off;
}

__device__ __forceinline__ float2 unpack_bf16x2(unsigned p) {
    float2 r;
    r.x = __uint_as_float(p << 16);
    r.y = __uint_as_float(p & 0xffff0000u);
    return r;
}

__device__ __forceinline__ unsigned pack_bf16x2(float a, float b) {
    __hip_bfloat162 h = __float22bfloat162_rn(make_float2(a, b));
    return *(unsigned*)&h;
}

__global__ void att_vec_kernel(const float* __restrict__ au, const float* __restrict__ Mu,
                               const float* __restrict__ ai, const float* __restrict__ Mi,
                               const float* __restrict__ as_, const float* __restrict__ Ms,
                               float* __restrict__ v) {
    int d = threadIdx.x;  // 64 threads
    float su = 0.f, si = 0.f, ss = 0.f;
    for (int e = 0; e < DD; ++e) {
        su += au[e] * Mu[e * DD + d];
        si += ai[e] * Mi[e * DD + d];
        ss += as_[e] * Ms[e * DD + d];
    }
    v[d] = su;
    v[DD + d] = si;
    v[2 * DD + d] = ss;
}

__device__ __forceinline__ int decode_row(int e, const int* rR, const int* fR, const int* gR) {
    if (e < 5 * NNZC) return (e / NNZC) * NN + rR[e];
    if (e < 6 * NNZC) return 5 * NN + fR[e - 5 * NNZC];
    return 5 * NN + UU + gR[e - 6 * NNZC];
}

__global__ void hist_kernel(const int* __restrict__ rR, const int* __restrict__ fR,
                            const int* __restrict__ gR, int* __restrict__ deg) {
    const int nTot = NGRAPH * NNZC;
    for (int e = blockIdx.x * blockDim.x + threadIdx.x; e < nTot; e += gridDim.x * blockDim.x) {
        atomicAdd(&deg[decode_row(e, rR, fR, gR)], 1);
    }
}

__global__ void scanA_kernel(const int* __restrict__ deg, int* __restrict__ partials) {
    __shared__ int lds[8];
    int base = blockIdx.x * SCAN_CHUNK + threadIdx.x * 8;
    int s = 0;
#pragma unroll
    for (int k = 0; k < 8; ++k) {
        int i = base + k;
        s += (i < MTOT) ? deg[i] : 0;
    }
    int incl = block_incl_scan(s, lds);
    if (threadIdx.x == 255) partials[blockIdx.x] = incl;
}

__global__ void scanB_kernel(int* __restrict__ partials) {
    __shared__ int lds[8];
    __shared__ int sOff;
    __shared__ int sTot;
    if (threadIdx.x == 0) sOff = 0;
    __syncthreads();
    for (int base = 0; base < NPART; base += 256) {
        int i = base + threadIdx.x;
        int v = (i < NPART) ? partials[i] : 0;
        int incl = block_incl_scan(v, lds);
        if (threadIdx.x == 255) sTot = incl;
        __syncthreads();
        if (i < NPART) partials[i] = sOff + incl - v;
        __syncthreads();
        if (threadIdx.x == 0) sOff += sTot;
        __syncthreads();
    }
}

// in-place exclusive scan of deg -> rowptr (START form)
__global__ void scanC_kernel(int* __restrict__ deg, const int* __restrict__ partials) {
    __shared__ int lds[8];
    int base = blockIdx.x * SCAN_CHUNK + threadIdx.x * 8;
    int v[8];
    int s = 0;
#pragma unroll
    for (int k = 0; k < 8; ++k) {
        int i = base + k;
        v[k] = (i < MTOT) ? deg[i] : 0;
        s += v[k];
    }
    int incl = block_incl_scan(s, lds);
    int run = incl - s + partials[blockIdx.x];
#pragma unroll
    for (int k = 0; k < 8; ++k) {
        int i = base + k;
        if (i < MTOT) deg[i] = run;
        run += v[k];
    }
}

__global__ void bucket_init_kernel(const int* __restrict__ rowptr, int* __restrict__ bucketCur) {
    int b = threadIdx.x;  // 256 threads, 1 block
    int fr = b * RPB;
    bucketCur[b] = (fr < MTOT) ? rowptr[fr] : NGRAPH * NNZC;
}

// Phase A: partition edges into NB row-range buckets (semi-coalesced appends)
__global__ void phaseA_kernel(const int* __restrict__ rR, const int* __restrict__ rC,
                              const float* __restrict__ rV,
                              const int* __restrict__ fR, const int* __restrict__ fC,
                              const float* __restrict__ fV,
                              const int* __restrict__ gR, const int* __restrict__ gC,
                              const float* __restrict__ gV,
                              int* __restrict__ bucketCur,
                              uint2* __restrict__ ecv, int* __restrict__ erow) {
    __shared__ int lcnt[NB];
    __shared__ int lbase[NB];
    const int nTot = NGRAPH * NNZC;
    int cbase = blockIdx.x * ACHUNK;
    if (cbase >= nTot) return;

    for (int b = threadIdx.x; b < NB; b += 256) lcnt[b] = 0;
    __syncthreads();
    // pass 1: count rows
#pragma unroll 4
    for (int k = 0; k < ACHUNK / 256; ++k) {
        int e = cbase + k * 256 + threadIdx.x;
        if (e < nTot) atomicAdd(&lcnt[decode_row(e, rR, fR, gR) / RPB], 1);
    }
    __syncthreads();
    // pass 2: reserve global space per bucket
    for (int b = threadIdx.x; b < NB; b += 256) {
        int n = lcnt[b];
        lbase[b] = n ? atomicAdd(&bucketCur[b], n) : 0;
    }
    __syncthreads();
    for (int b = threadIdx.x; b < NB; b += 256) lcnt[b] = 0;
    __syncthreads();
    // pass 3: write
#pragma unroll 4
    for (int k = 0; k < ACHUNK / 256; ++k) {
        int e = cbase + k * 256 + threadIdx.x;
        if (e >= nTot) continue;
        int grow, c;
        float v;
        if (e < 5 * NNZC) {
            grow = (e / NNZC) * NN + rR[e]; c = rC[e]; v = rV[e];
        } else if (e < 6 * NNZC) {
            int kk = e - 5 * NNZC;
            grow = 5 * NN + fR[kk]; c = fC[kk]; v = fV[kk];
        } else {
            int kk = e - 6 * NNZC;
            grow = 5 * NN + UU + gR[kk]; c = gC[kk]; v = gV[kk];
        }
        int b = grow / RPB;
        int pos = lbase[b] + atomicAdd(&lcnt[b], 1);
        ecv[pos] = make_uint2((unsigned)c, __float_as_uint(v));
        erow[pos] = grow;
    }
}

// Phase B: per-bucket scatter to exact CSR slots (L2-resident window).
// rowptr transitions START form -> END form.
__global__ __launch_bounds__(1024) void phaseB_kernel(const int* __restrict__ bucketCur,
                                                      int* __restrict__ rowptr,
                                                      const uint2* __restrict__ ecv,
                                                      const int* __restrict__ erow,
                                                      uint2* __restrict__ edata) {
    int b = blockIdx.x;
    int firstRow = b * RPB;
    if (firstRow >= MTOT) return;
    __shared__ int sBeg;
    if (threadIdx.x == 0) sBeg = rowptr[firstRow];
    __syncthreads();
    int endE = bucketCur[b];
    for (int i = sBeg + threadIdx.x; i < endE; i += 1024) {
        int grow = erow[i];
        uint2 cv = ecv[i];
        int pos = atomicAdd(&rowptr[grow], 1);
        edata[pos] = cv;
    }
}

// Split-wave SpMM: 2 edges in flight per wave, 32 lanes x 2 dims each.
// MODE 0: gather f32 (xlo/xhi split) -> outB bf16x2 (rating L1)
// MODE 1: gather bf16 xB -> m=0.5*(acc+selfB); outB bf16x2; wOut=tanh(dot(m,v)) (rating L2)
// MODE 2: gather f32 -> outF = l2norm(acc) (social L1)
// MODE 3: gather f32 -> outF = 0.5*(selfF + l2norm(acc)) (social L2)
template <int MODE>
__global__ void spmm2_kernel(const int* __restrict__ rowptr, int rowBase,
                             const uint2* __restrict__ edata,
                             const float* __restrict__ xloF, const float* __restrict__ xhiF,
                             const unsigned* __restrict__ xB, int split,
                             const float* __restrict__ selfF, const unsigned* __restrict__ selfB,
                             const float* __restrict__ vvec,
                             unsigned* __restrict__ outB, float* __restrict__ outF,
                             float* __restrict__ wOut, int nRows) {
    int lane = threadIdx.x & 63;
    int half = lane >> 5;
    int hl = lane & 31;
    int row = blockIdx.x * (blockDim.x >> 6) + (threadIdx.x >> 6);
    if (row >= nRows) return;
    int g = rowBase + row;
    int start = (g == 0) ? 0 : rowptr[g - 1];
    int end = rowptr[g];
    float2 acc = make_float2(0.f, 0.f);
    for (int j0 = start; j0 < end; j0 += 64) {
        uint2 md = make_uint2(0u, 0u);
        if (j0 + lane < end) md = edata[j0 + lane];
        int cnt = min(end - j0, 64);
        for (int j = 0; j < cnt; j += 2) {
            int jj = j + half;
            int c = __shfl((int)md.x, jj, 64);
            float v = __uint_as_float((unsigned)__shfl((int)md.y, jj, 64));
            if (jj >= cnt) { v = 0.f; c = 0; }
            float2 xv;
            if (MODE == 1) {
                xv = unpack_bf16x2(xB[(size_t)c * 32 + hl]);
            } else {
                const float* src = (c < split) ? (xloF + (size_t)c * DD)
                                               : (xhiF + (size_t)(c - split) * DD);
                xv = *(const float2*)(src + 2 * hl);
            }
            acc.x += v * xv.x;
            acc.y += v * xv.y;
        }
    }
    acc.x += __shfl_xor(acc.x, 32, 64);
    acc.y += __shfl_xor(acc.y, 32, 64);

    size_t ro = (size_t)row * 32 + hl;
    if (MODE == 0) {
        if (half == 0) outB[ro] = pack_bf16x2(acc.x, acc.y);
    } else if (MODE == 1) {
        float2 sv = unpack_bf16x2(selfB[ro]);
        float m0 = 0.5f * (acc.x + sv.x);
        float m1 = 0.5f * (acc.y + sv.y);
        if (half == 0) outB[ro] = pack_bf16x2(m0, m1);
        const float* v = (row < UU) ? vvec : (vvec + DD);
        float partial = m0 * v[2 * hl] + m1 * v[2 * hl + 1];
        float s = wave_sum(partial) * 0.5f;
        if (lane == 0) wOut[row] = tanhf(s);
    } else if (MODE == 2) {
        float nrm = sqrtf(wave_sum(acc.x * acc.x + acc.y * acc.y) * 0.5f);
        float inv = 1.f / fmaxf(nrm, 1e-12f);
        if (half == 0)
            *(float2*)(outF + (size_t)row * DD + 2 * hl) = make_float2(acc.x * inv, acc.y * inv);
    } else {
        float nrm = sqrtf(wave_sum(acc.x * acc.x + acc.y * acc.y) * 0.5f);
        float inv = 1.f / fmaxf(nrm, 1e-12f);
        float2 sv = *(const float2*)(selfF + (size_t)row * DD + 2 * hl);
        if (half == 0)
            *(float2*)(outF + (size_t)row * DD + 2 * hl) =
                make_float2(0.5f * (sv.x + acc.x * inv), 0.5f * (sv.y + acc.y * inv));
    }
}

// softmax over 5 channels per row (bf16 channel embeddings)
__global__ void mix5_kernel(const __hip_bfloat16* __restrict__ chanEmb,
                            const float* __restrict__ w,
                            int rowOff, int nRows, int scoreStride,
                            float* __restrict__ scoresOut, float* __restrict__ mixedOut) {
    int lane = threadIdx.x & 63;
    int n = blockIdx.x * (blockDim.x >> 6) + (threadIdx.x >> 6);
    if (n >= nRows) return;
    int gn = n + rowOff;
    float sw[5];
    float mx = -2.0f;
#pragma unroll
    for (int c = 0; c < 5; ++c) {
        sw[c] = w[(size_t)c * NN + gn];
        mx = fmaxf(mx, sw[c]);
    }
    float sum = 0.f;
#pragma unroll
    for (int c = 0; c < 5; ++c) {
        sw[c] = expf(sw[c] - mx);
        sum += sw[c];
    }
    float inv = 1.0f / sum;
    float acc = 0.f;
#pragma unroll
    for (int c = 0; c < 5; ++c) {
        float s = sw[c] * inv;
        if (lane == c) scoresOut[(size_t)c * scoreStride + n] = s;
        acc += s * __bfloat162float(chanEmb[((size_t)c * NN + gn) * DD + lane]);
    }
    mixedOut[(size_t)n * DD + lane] = acc;
}

// social 2-channel softmax fuse + adaptive final combine
__global__ void social_mix_final_kernel(const float* __restrict__ e0, const float* __restrict__ e1,
                                        const float* __restrict__ vs,
                                        const float* __restrict__ mixedRU,
                                        const float* __restrict__ adaptive,
                                        float* __restrict__ scoresOut,
                                        float* __restrict__ outMU) {
    int lane = threadIdx.x & 63;
    int n = blockIdx.x * (blockDim.x >> 6) + (threadIdx.x >> 6);
    if (n >= UU) return;
    size_t idx = (size_t)n * DD + lane;
    float a = e0[idx];
    float b = e1[idx];
    float v = vs[lane];
    float w0 = tanhf(wave_sum(a * v));
    float w1 = tanhf(wave_sum(b * v));
    float mx = fmaxf(w0, w1);
    float x0 = expf(w0 - mx);
    float x1 = expf(w1 - mx);
    float inv = 1.0f / (x0 + x1);
    float s0 = x0 * inv;
    float s1 = x1 * inv;
    if (lane == 0) {
        scoresOut[n] = s0;
        scoresOut[UU + n] = s1;
    }
    float ms = s0 * a + s1 * b;
    float mru = mixedRU[idx];
    float num = wave_sum(mru * ms);
    float na = sqrtf(wave_sum(mru * mru));
    float nb = sqrtf(wave_sum(ms * ms));
    float denom = fmaxf(na, 1e-8f) * fmaxf(nb, 1e-8f);
    float sim = num / denom;
    float rate = 1.0f / (2.0f + fmaxf(sim, 0.f) * adaptive[n]);
    outMU[idx] = mru + ms * rate;
}

extern "C" void kernel_launch(void* const* d_in, const int* in_sizes, int n_in,
                              void* d_out, int out_size, void* d_ws, size_t ws_size,
                              hipStream_t stream) {
    const int* r_rows = (const int*)d_in[0];
    const int* r_cols = (const int*)d_in[1];
    const float* r_vals = (const float*)d_in[2];
    const int* f_rows = (const int*)d_in[3];
    const int* f_cols = (const int*)d_in[4];
    const float* f_vals = (const float*)d_in[5];
    const int* g_rows = (const int*)d_in[6];
    const int* g_cols = (const int*)d_in[7];
    const float* g_vals = (const float*)d_in[8];
    const float* rue = (const float*)d_in[9];
    const float* rie = (const float*)d_in[10];
    const float* femb = (const float*)d_in[11];
    const float* gemb = (const float*)d_in[12];
    const float* uaw = (const float*)d_in[13];
    const float* uamw = (const float*)d_in[14];
    const float* iaw = (const float*)d_in[15];
    const float* iamw = (const float*)d_in[16];
    const float* saw = (const float*)d_in[17];
    const float* samw = (const float*)d_in[18];
    const float* adapt = (const float*)d_in[19];

    // ws layout (float units):
    float* ws = (float*)d_ws;
    int* rowptr = (int*)ws;                              // 870,016
    int* partials = rowptr + 870016;                     // 2,048
    int* bucketCur = partials + 2048;                    // 256
    uint2* edata = (uint2*)(bucketCur + 256);            // 7M uint2 = 14M floats
    unsigned* AtmpB = (unsigned*)(ws + 872320 + 14000000);       // NN*32 uints (bf16x2)
    __hip_bfloat16* chanMean = (__hip_bfloat16*)(AtmpB + (size_t)NN * 32);  // 5*NN*64 bf16 (24M floats)
    float* wrat = (float*)ws + 43672320;                 // 5*NN f32
    float* vvec = wrat + (size_t)5 * NN;                 // 192 f32

    // aliases inside chanMean region (dead before rating passes / after mix5)
    uint2* ecv = (uint2*)chanMean;                       // 7M uint2 = 14M floats
    int* erow = (int*)chanMean + 28000000;               // 7M ints
    float* socL1 = (float*)chanMean;                     // UU*DD f32 (after mix5)
    float* socM0 = socL1 + (size_t)UU * DD;
    float* socM1 = socM0 + (size_t)UU * DD;
    float* mixedRU = (float*)AtmpB;                      // AtmpB dead after rating loop

    float* out = (float*)d_out;
    float* oUS = out;                               // [5, UU]
    float* oIS = oUS + (size_t)5 * UU;              // [5, II]
    float* oSS = oIS + (size_t)5 * II;              // [2, UU]
    float* oMU = oSS + (size_t)2 * UU;              // [UU, DD]
    float* oMI = oMU + (size_t)UU * DD;             // [II, DD]

    const dim3 blk(256);
    const int gridN = (NN + 3) / 4;
    const int gridU = (UU + 3) / 4;
    const int gridI = (II + 3) / 4;
    const int gridEdge = 4096;
    const int gridA = (NGRAPH * NNZC + ACHUNK - 1) / ACHUNK;  // 855

    att_vec_kernel<<<1, 64, 0, stream>>>(uaw, uamw, iaw, iamw, saw, samw, vvec);

    // ---- build CSR for all 7 graphs (binned two-phase) ----
    hipMemsetAsync(rowptr, 0, MTOT * sizeof(int), stream);
    hist_kernel<<<gridEdge, blk, 0, stream>>>(r_rows, f_rows, g_rows, rowptr);
    scanA_kernel<<<NPART, blk, 0, stream>>>(rowptr, partials);
    scanB_kernel<<<1, blk, 0, stream>>>(partials);
    scanC_kernel<<<NPART, blk, 0, stream>>>(rowptr, partials);
    bucket_init_kernel<<<1, NB, 0, stream>>>(rowptr, bucketCur);
    phaseA_kernel<<<gridA, blk, 0, stream>>>(r_rows, r_cols, r_vals,
                                             f_rows, f_cols, f_vals,
                                             g_rows, g_cols, g_vals,
                                             bucketCur, ecv, erow);
    phaseB_kernel<<<NB, 1024, 0, stream>>>(bucketCur, rowptr, ecv, erow, edata);

    // ---- rating channels ----
    for (int c = 0; c < 5; ++c) {
        int rb = c * NN;
        spmm2_kernel<0><<<gridN, blk, 0, stream>>>(
            rowptr, rb, edata,
            rue + (size_t)c * UU * DD, rie + (size_t)c * II * DD, nullptr, UU,
            nullptr, nullptr, nullptr, AtmpB, nullptr, nullptr, NN);
        spmm2_kernel<1><<<gridN, blk, 0, stream>>>(
            rowptr, rb, edata,
            nullptr, nullptr, AtmpB, NN,
            nullptr, AtmpB, vvec,
            (unsigned*)(chanMean + (size_t)c * NN * DD), nullptr, wrat + (size_t)c * NN, NN);
    }

    // ---- attention fuse (rating) ----
    mix5_kernel<<<gridI, blk, 0, stream>>>(chanMean, wrat, UU, II, II, oIS, oMI);
    mix5_kernel<<<gridU, blk, 0, stream>>>(chanMean, wrat, 0, UU, UU, oUS, mixedRU);

    // ---- social: friend (graph 5) ----
    {
        int rb = 5 * NN;
        spmm2_kernel<2><<<gridU, blk, 0, stream>>>(rowptr, rb, edata,
                                                   femb, femb, nullptr, UU,
                                                   nullptr, nullptr, nullptr,
                                                   nullptr, socL1, nullptr, UU);
        spmm2_kernel<3><<<gridU, blk, 0, stream>>>(rowptr, rb, edata,
                                                   socL1, socL1, nullptr, UU,
                                                   socL1, nullptr, nullptr,
                                                   nullptr, socM0, nullptr, UU);
    }
    // ---- social: group (graph 6) ----
    {
        int rb = 5 * NN + UU;
        spmm2_kernel<2><<<gridU, blk, 0, stream>>>(rowptr, rb, edata,
                                                   gemb, gemb, nullptr, UU,
                                                   nullptr, nullptr, nullptr,
                                                   nullptr, socL1, nullptr, UU);
        spmm2_kernel<3><<<gridU, blk, 0, stream>>>(rowptr, rb, edata,
                                                   socL1, socL1, nullptr, UU,
                                                   socL1, nullptr, nullptr,
                                                   nullptr, socM1, nullptr, UU);
    }

    // ---- social fuse + adaptive combine ----
    social_mix_final_kernel<<<gridU, blk, 0, stream>>>(socM0, socM1, vvec + 2 * DD,
                                                       mixedRU, adapt, oSS, oMU);
}

// Round 4
// 1008.695 us; speedup vs baseline: 3.2966x; 1.8147x over previous
//
#include <hip/hip_runtime.h>
#include <hip/hip_bf16.h>

#define UU 60000
#define II 90000
#define DD 64
#define NN 150000
#define NNZC 1000000
#define NTOT 7000000
#define MTOT 870000           // 5*NN + 2*UU
#define ROW_S0 750000         // start of social rows (5*NN)
#define NBR 733               // rating buckets (1024 rows each)
#define NBS 313               // social buckets (384 rows each)
#define NBCK 1046
#define CAPE 8192             // LDS sort capacity (edges)
#define ACHUNK 16384          // edges per phase-A block

__device__ __forceinline__ float wave_sum(float x) {
#pragma unroll
    for (int m = 32; m >= 1; m >>= 1) x += __shfl_xor(x, m, 64);
    return x;
}

__device__ __forceinline__ int wave_incl_scan(int x) {
    int lane = threadIdx.x & 63;
#pragma unroll
    for (int d = 1; d < 64; d <<= 1) {
        int y = __shfl_up(x, d, 64);
        if (lane >= d) x += y;
    }
    return x;
}

__device__ int block_incl_scan(int x, int* lds) {
    int wid = threadIdx.x >> 6, lane = threadIdx.x & 63;
    int ws_ = wave_incl_scan(x);
    if (lane == 63) lds[wid] = ws_;
    __syncthreads();
    int off = 0;
    for (int w = 0; w < wid; ++w) off += lds[w];
    __syncthreads();
    return ws_ + off;
}

__device__ __forceinline__ float2 unpack_bf16x2(unsigned p) {
    float2 r;
    r.x = __uint_as_float(p << 16);
    r.y = __uint_as_float(p & 0xffff0000u);
    return r;
}

__device__ __forceinline__ unsigned pack_bf16x2(float a, float b) {
    __hip_bfloat162 h = __float22bfloat162_rn(make_float2(a, b));
    return *(unsigned*)&h;
}

__device__ __forceinline__ uint2 pack4(float4 m) {
    return make_uint2(pack_bf16x2(m.x, m.y), pack_bf16x2(m.z, m.w));
}

__device__ __forceinline__ float4 unpack4(uint2 p) {
    float2 a = unpack_bf16x2(p.x), b = unpack_bf16x2(p.y);
    return make_float4(a.x, a.y, b.x, b.y);
}

__device__ __forceinline__ void qred(float4& a) {
    a.x += __shfl_xor(a.x, 16, 64); a.y += __shfl_xor(a.y, 16, 64);
    a.z += __shfl_xor(a.z, 16, 64); a.w += __shfl_xor(a.w, 16, 64);
    a.x += __shfl_xor(a.x, 32, 64); a.y += __shfl_xor(a.y, 32, 64);
    a.z += __shfl_xor(a.z, 32, 64); a.w += __shfl_xor(a.w, 32, 64);
}

__device__ __forceinline__ int bid_of(int grow) {
    return (grow < ROW_S0) ? (grow >> 10) : NBR + (grow - ROW_S0) / 384;
}

__device__ __forceinline__ int decode_row(int e, const int* rR, const int* fR, const int* gR) {
    if (e < 5 * NNZC) return (e / NNZC) * NN + rR[e];
    if (e < 6 * NNZC) return ROW_S0 + fR[e - 5 * NNZC];
    return ROW_S0 + UU + gR[e - 6 * NNZC];
}

__global__ void att_vec_kernel(const float* __restrict__ au, const float* __restrict__ Mu,
                               const float* __restrict__ ai, const float* __restrict__ Mi,
                               const float* __restrict__ as_, const float* __restrict__ Ms,
                               float* __restrict__ v) {
    int d = threadIdx.x;  // 64 threads
    float su = 0.f, si = 0.f, ss = 0.f;
    for (int e = 0; e < DD; ++e) {
        su += au[e] * Mu[e * DD + d];
        si += ai[e] * Mi[e * DD + d];
        ss += as_[e] * Ms[e * DD + d];
    }
    v[d] = su;
    v[DD + d] = si;
    v[2 * DD + d] = ss;
}

// bucket-level histogram of all 7M edges
__global__ void bcount_kernel(const int* __restrict__ rR, const int* __restrict__ fR,
                              const int* __restrict__ gR, int* __restrict__ bCnt) {
    __shared__ int l[NBCK];
    for (int i = threadIdx.x; i < NBCK; i += 256) l[i] = 0;
    __syncthreads();
    for (int e = blockIdx.x * blockDim.x + threadIdx.x; e < NTOT; e += gridDim.x * blockDim.x)
        atomicAdd(&l[bid_of(decode_row(e, rR, fR, gR))], 1);
    __syncthreads();
    for (int i = threadIdx.x; i < NBCK; i += 256)
        if (l[i]) atomicAdd(&bCnt[i], l[i]);
}

// single-block exclusive scan of bucket counts -> bStart, bCur; sentinel rowptr[MTOT]
__global__ void bscan_kernel(const int* __restrict__ bCnt, int* __restrict__ bStart,
                             int* __restrict__ bCur, int* __restrict__ rowptr) {
    __shared__ int lds8[8];
    __shared__ int sOff;
    if (threadIdx.x == 0) sOff = 0;
    __syncthreads();
    for (int base = 0; base < NBCK; base += 256) {
        int i = base + threadIdx.x;
        int v = (i < NBCK) ? bCnt[i] : 0;
        int incl = block_incl_scan(v, lds8);
        int excl = sOff + incl - v;
        if (i < NBCK) { bStart[i] = excl; bCur[i] = excl; }
        __syncthreads();
        if (threadIdx.x == 255) sOff += incl;
        __syncthreads();
    }
    if (threadIdx.x == 0) { bStart[NBCK] = sOff; rowptr[MTOT] = sOff; }
}

// Phase A: bin edges into NBCK bucket staging regions; entry = (lrow<<18 | c, val)
__global__ __launch_bounds__(256) void phaseA_kernel(
        const int* __restrict__ rR, const int* __restrict__ rC, const float* __restrict__ rV,
        const int* __restrict__ fR, const int* __restrict__ fC, const float* __restrict__ fV,
        const int* __restrict__ gR, const int* __restrict__ gC, const float* __restrict__ gV,
        int* __restrict__ bCur, uint2* __restrict__ ecv) {
    __shared__ int sGrow[ACHUNK];
    __shared__ int lcnt[NBCK];
    __shared__ int lbase[NBCK];
    int cbase = blockIdx.x * ACHUNK;
    if (cbase >= NTOT) return;
    for (int b = threadIdx.x; b < NBCK; b += 256) lcnt[b] = 0;
    __syncthreads();
    // pass 1: decode rows, cache grow, count buckets
    for (int k = 0; k < ACHUNK / 256; ++k) {
        int idx = k * 256 + threadIdx.x;
        int e = cbase + idx;
        if (e < NTOT) {
            int grow = decode_row(e, rR, fR, gR);
            sGrow[idx] = grow;
            atomicAdd(&lcnt[bid_of(grow)], 1);
        }
    }
    __syncthreads();
    // pass 2: reserve global staging space
    for (int b = threadIdx.x; b < NBCK; b += 256) {
        int n = lcnt[b];
        lbase[b] = n ? atomicAdd(&bCur[b], n) : 0;
    }
    __syncthreads();
    for (int b = threadIdx.x; b < NBCK; b += 256) lcnt[b] = 0;
    __syncthreads();
    // pass 3: write packed entries
    for (int k = 0; k < ACHUNK / 256; ++k) {
        int idx = k * 256 + threadIdx.x;
        int e = cbase + idx;
        if (e >= NTOT) continue;
        int grow = sGrow[idx];
        int c; float v;
        if (e < 5 * NNZC) { c = rC[e]; v = rV[e]; }
        else if (e < 6 * NNZC) { int kk = e - 5 * NNZC; c = fC[kk]; v = fV[kk]; }
        else { int kk = e - 6 * NNZC; c = gC[kk]; v = gV[kk]; }
        int b = bid_of(grow);
        int lrow = (grow < ROW_S0) ? (grow & 1023) : ((grow - ROW_S0) % 384);
        int pos = lbase[b] + atomicAdd(&lcnt[b], 1);
        ecv[pos] = make_uint2(((unsigned)lrow << 18) | (unsigned)c, __float_as_uint(v));
    }
}

// Phase B: per-bucket LDS counting sort -> coalesced edata writes; also writes rowptr
__global__ __launch_bounds__(256) void phaseB_kernel(const int* __restrict__ bStart,
                                                     int* __restrict__ rowptr,
                                                     const uint2* __restrict__ ecv,
                                                     uint2* __restrict__ edata) {
    __shared__ uint2 sbuf[CAPE];   // 64 KB
    __shared__ int off[1024];
    __shared__ int lds8[8];
    int b = blockIdx.x;
    int firstRow = (b < NBR) ? (b << 10) : ROW_S0 + (b - NBR) * 384;
    int rowEnd = (b < NBR) ? min((b + 1) << 10, ROW_S0)
                           : min(ROW_S0 + (b - NBR + 1) * 384, MTOT);
    int nRows = rowEnd - firstRow;
    int eStart = bStart[b];
    int count = bStart[b + 1] - eStart;
    for (int i = threadIdx.x; i < nRows; i += 256) off[i] = 0;
    __syncthreads();
    // histogram by local row
    for (int i = threadIdx.x; i < count; i += 256)
        atomicAdd(&off[ecv[eStart + i].x >> 18], 1);
    __syncthreads();
    // scan (4 rows per thread), emit rowptr
    int base4 = threadIdx.x * 4;
    int v4[4], s = 0;
#pragma unroll
    for (int k = 0; k < 4; ++k) {
        int i = base4 + k;
        v4[k] = (i < nRows) ? off[i] : 0;
        s += v4[k];
    }
    int incl = block_incl_scan(s, lds8);
    int run = incl - s;
#pragma unroll
    for (int k = 0; k < 4; ++k) {
        int i = base4 + k;
        if (i < nRows) { rowptr[firstRow + i] = eStart + run; off[i] = run; }
        run += v4[k];
    }
    __syncthreads();
    if (count <= CAPE) {
        for (int i = threadIdx.x; i < count; i += 256) {
            uint2 e = ecv[eStart + i];
            int pos = atomicAdd(&off[e.x >> 18], 1);
            sbuf[pos] = make_uint2(e.x & 0x3FFFFu, e.y);
        }
        __syncthreads();
        for (int i = threadIdx.x; i < count; i += 256) edata[eStart + i] = sbuf[i];
    } else {
        // overflow fallback: direct scatter (rare)
        for (int i = threadIdx.x; i < count; i += 256) {
            uint2 e = ecv[eStart + i];
            int pos = atomicAdd(&off[e.x >> 18], 1);
            edata[eStart + pos] = make_uint2(e.x & 0x3FFFFu, e.y);
        }
    }
}

// convert rating channel (user f32 + item f32) -> contiguous bf16x4 table [NN][16]
__global__ void cvt_rating_kernel(const float4* __restrict__ u, const float4* __restrict__ it,
                                  uint2* __restrict__ tbl) {
    int i = blockIdx.x * 256 + threadIdx.x;
    if (i >= NN * 16) return;
    int row = i >> 4, h = i & 15;
    float4 x = (row < UU) ? u[(size_t)row * 16 + h] : it[(size_t)(row - UU) * 16 + h];
    tbl[i] = pack4(x);
}

__global__ void cvt_u_kernel(const float4* __restrict__ src, uint2* __restrict__ tbl) {
    int i = blockIdx.x * 256 + threadIdx.x;
    if (i >= UU * 16) return;
    tbl[i] = pack4(src[i]);
}

// 4 edges in flight per wave; 16 lanes x 4 dims per edge. All gathers bf16x4.
// MODE 0: out bf16 = acc                          (rating L1)
// MODE 1: m=0.5*(acc+self); out bf16; wOut=tanh   (rating L2)
// MODE 2: out bf16 = l2norm(acc)                  (social L1)
// MODE 3: out f32  = 0.5*(self + l2norm(acc))     (social L2)
template <int MODE>
__global__ __launch_bounds__(256) void spmm4_kernel(
        const int* __restrict__ rowptr, int rowBase,
        const uint2* __restrict__ edata, const uint2* __restrict__ tbl,
        const uint2* __restrict__ selfB, const float* __restrict__ vvec,
        uint2* __restrict__ outB, float4* __restrict__ outF,
        float* __restrict__ wOut, int nRows) {
    int lane = threadIdx.x & 63;
    int q = lane >> 4;      // quarter: which of 4 concurrent edges
    int h = lane & 15;      // dim group: dims 4h..4h+3
    int row = blockIdx.x * (blockDim.x >> 6) + (threadIdx.x >> 6);
    if (row >= nRows) return;
    int g = rowBase + row;
    int start = rowptr[g], end = rowptr[g + 1];
    float4 acc = make_float4(0.f, 0.f, 0.f, 0.f);
    for (int j0 = start; j0 < end; j0 += 64) {
        uint2 md = make_uint2(0u, 0u);
        if (j0 + lane < end) md = edata[j0 + lane];
        int cnt = min(end - j0, 64);
        for (int j = 0; j < cnt; j += 4) {
            int jj = j + q;
            int c = __shfl((int)md.x, jj, 64);
            float v = __uint_as_float((unsigned)__shfl((int)md.y, jj, 64));
            if (jj >= cnt) { v = 0.f; c = 0; }
            float4 xv = unpack4(tbl[(size_t)c * 16 + h]);
            acc.x += v * xv.x; acc.y += v * xv.y;
            acc.z += v * xv.z; acc.w += v * xv.w;
        }
    }
    qred(acc);  // combine quarters; every lane now has full sums for its 4 dims

    size_t ro = (size_t)row * 16 + h;
    if (MODE == 0) {
        if (q == 0) outB[ro] = pack4(acc);
    } else if (MODE == 1) {
        float4 sv = unpack4(selfB[ro]);
        float4 m = make_float4(0.5f * (acc.x + sv.x), 0.5f * (acc.y + sv.y),
                               0.5f * (acc.z + sv.z), 0.5f * (acc.w + sv.w));
        if (q == 0) outB[ro] = pack4(m);
        const float* vv = (row < UU) ? vvec : (vvec + DD);
        float4 vw = *(const float4*)(vv + 4 * h);
        float partial = m.x * vw.x + m.y * vw.y + m.z * vw.z + m.w * vw.w;
        float sdot = wave_sum(partial) * 0.25f;
        if (lane == 0) wOut[row] = tanhf(sdot);
    } else if (MODE == 2) {
        float n2 = wave_sum(acc.x * acc.x + acc.y * acc.y + acc.z * acc.z + acc.w * acc.w) * 0.25f;
        float inv = 1.f / fmaxf(sqrtf(n2), 1e-12f);
        if (q == 0) outB[ro] = pack4(make_float4(acc.x * inv, acc.y * inv, acc.z * inv, acc.w * inv));
    } else {
        float n2 = wave_sum(acc.x * acc.x + acc.y * acc.y + acc.z * acc.z + acc.w * acc.w) * 0.25f;
        float inv = 1.f / fmaxf(sqrtf(n2), 1e-12f);
        float4 sv = unpack4(selfB[ro]);
        if (q == 0)
            outF[ro] = make_float4(0.5f * (sv.x + acc.x * inv), 0.5f * (sv.y + acc.y * inv),
                                   0.5f * (sv.z + acc.z * inv), 0.5f * (sv.w + acc.w * inv));
    }
}

// softmax over 5 channels per row (bf16 channel embeddings)
__global__ void mix5_kernel(const __hip_bfloat16* __restrict__ chanEmb,
                            const float* __restrict__ w,
                            int rowOff, int nRows, int scoreStride,
                            float* __restrict__ scoresOut, float* __restrict__ mixedOut) {
    int lane = threadIdx.x & 63;
    int n = blockIdx.x * (blockDim.x >> 6) + (threadIdx.x >> 6);
    if (n >= nRows) return;
    int gn = n + rowOff;
    float sw[5];
    float mx = -2.0f;
#pragma unroll
    for (int c = 0; c < 5; ++c) {
        sw[c] = w[(size_t)c * NN + gn];
        mx = fmaxf(mx, sw[c]);
    }
    float sum = 0.f;
#pragma unroll
    for (int c = 0; c < 5; ++c) {
        sw[c] = expf(sw[c] - mx);
        sum += sw[c];
    }
    float inv = 1.0f / sum;
    float acc = 0.f;
#pragma unroll
    for (int c = 0; c < 5; ++c) {
        float s = sw[c] * inv;
        if (lane == c) scoresOut[(size_t)c * scoreStride + n] = s;
        acc += s * __bfloat162float(chanEmb[((size_t)c * NN + gn) * DD + lane]);
    }
    mixedOut[(size_t)n * DD + lane] = acc;
}

// social 2-channel softmax fuse + adaptive final combine
__global__ void social_mix_final_kernel(const float* __restrict__ e0, const float* __restrict__ e1,
                                        const float* __restrict__ vs,
                                        const float* __restrict__ mixedRU,
                                        const float* __restrict__ adaptive,
                                        float* __restrict__ scoresOut,
                                        float* __restrict__ outMU) {
    int lane = threadIdx.x & 63;
    int n = blockIdx.x * (blockDim.x >> 6) + (threadIdx.x >> 6);
    if (n >= UU) return;
    size_t idx = (size_t)n * DD + lane;
    float a = e0[idx];
    float b = e1[idx];
    float v = vs[lane];
    float w0 = tanhf(wave_sum(a * v));
    float w1 = tanhf(wave_sum(b * v));
    float mx = fmaxf(w0, w1);
    float x0 = expf(w0 - mx);
    float x1 = expf(w1 - mx);
    float inv = 1.0f / (x0 + x1);
    float s0 = x0 * inv;
    float s1 = x1 * inv;
    if (lane == 0) {
        scoresOut[n] = s0;
        scoresOut[UU + n] = s1;
    }
    float ms = s0 * a + s1 * b;
    float mru = mixedRU[idx];
    float num = wave_sum(mru * ms);
    float na = sqrtf(wave_sum(mru * mru));
    float nb = sqrtf(wave_sum(ms * ms));
    float denom = fmaxf(na, 1e-8f) * fmaxf(nb, 1e-8f);
    float sim = num / denom;
    float rate = 1.0f / (2.0f + fmaxf(sim, 0.f) * adaptive[n]);
    outMU[idx] = mru + ms * rate;
}

extern "C" void kernel_launch(void* const* d_in, const int* in_sizes, int n_in,
                              void* d_out, int out_size, void* d_ws, size_t ws_size,
                              hipStream_t stream) {
    const int* r_rows = (const int*)d_in[0];
    const int* r_cols = (const int*)d_in[1];
    const float* r_vals = (const float*)d_in[2];
    const int* f_rows = (const int*)d_in[3];
    const int* f_cols = (const int*)d_in[4];
    const float* f_vals = (const float*)d_in[5];
    const int* g_rows = (const int*)d_in[6];
    const int* g_cols = (const int*)d_in[7];
    const float* g_vals = (const float*)d_in[8];
    const float* rue = (const float*)d_in[9];
    const float* rie = (const float*)d_in[10];
    const float* femb = (const float*)d_in[11];
    const float* gemb = (const float*)d_in[12];
    const float* uaw = (const float*)d_in[13];
    const float* uamw = (const float*)d_in[14];
    const float* iaw = (const float*)d_in[15];
    const float* iamw = (const float*)d_in[16];
    const float* saw = (const float*)d_in[17];
    const float* samw = (const float*)d_in[18];
    const float* adapt = (const float*)d_in[19];

    // ws layout (float units) — total ≈ 53.6M floats ≈ 215 MB
    float* ws = (float*)d_ws;
    size_t o = 0;
    int* rowptr = (int*)(ws + o); o += 870016;     // MTOT+1
    int* bStart = (int*)(ws + o); o += 2048;       // NBCK+1
    int* bCur   = (int*)(ws + o); o += 2048;
    int* bCnt   = (int*)(ws + o); o += 2048;
    float* Ebase = ws + o; o += 14000000;          // ecv staging; later tables
    float* edF   = ws + o; o += 14000000;          // edata
    float* cmBase = ws + o; o += 24000000;         // chanMean; later social temps
    float* wrat = ws + o; o += 750016;
    float* vvec = ws + o; o += 192;

    uint2* ecv = (uint2*)Ebase;
    uint2* edata = (uint2*)edF;
    // post-build aliases in the ecv region:
    uint2* tblB  = (uint2*)Ebase;                          // NN*16
    uint2* AtmpB = (uint2*)(Ebase + 4800000);              // NN*16
    float* mixedRU = Ebase + 4800000;                      // after rating loop
    uint2* fgB0  = (uint2*)(Ebase + 9600000);              // UU*16
    uint2* fgB1  = (uint2*)(Ebase + 11520000);             // UU*16
    // chanMean region + social-phase aliases:
    __hip_bfloat16* chanMean = (__hip_bfloat16*)cmBase;    // 5*NN*64 bf16
    uint2* socL1B = (uint2*)cmBase;                        // UU*16 (after mix5)
    float* socM0 = cmBase + 2000000;                       // UU*64 f32
    float* socM1 = cmBase + 6000000;                       // UU*64 f32

    float* out = (float*)d_out;
    float* oUS = out;
    float* oIS = oUS + (size_t)5 * UU;
    float* oSS = oIS + (size_t)5 * II;
    float* oMU = oSS + (size_t)2 * UU;
    float* oMI = oMU + (size_t)UU * DD;

    const dim3 blk(256);
    const int gridN = (NN + 3) / 4;
    const int gridU = (UU + 3) / 4;
    const int gridI = (II + 3) / 4;
    const int gridA = (NTOT + ACHUNK - 1) / ACHUNK;   // 428
    const int gridCvtN = (NN * 16 + 255) / 256;
    const int gridCvtU = (UU * 16 + 255) / 256;

    att_vec_kernel<<<1, 64, 0, stream>>>(uaw, uamw, iaw, iamw, saw, samw, vvec);

    // ---- build sorted CSR for all 7 graphs ----
    hipMemsetAsync(bCnt, 0, NBCK * sizeof(int), stream);
    bcount_kernel<<<512, blk, 0, stream>>>(r_rows, f_rows, g_rows, bCnt);
    bscan_kernel<<<1, blk, 0, stream>>>(bCnt, bStart, bCur, rowptr);
    phaseA_kernel<<<gridA, blk, 0, stream>>>(r_rows, r_cols, r_vals,
                                             f_rows, f_cols, f_vals,
                                             g_rows, g_cols, g_vals, bCur, ecv);
    phaseB_kernel<<<NBCK, blk, 0, stream>>>(bStart, rowptr, ecv, edata);

    // ---- convert social tables (ecv region now free) ----
    cvt_u_kernel<<<gridCvtU, blk, 0, stream>>>((const float4*)femb, fgB0);
    cvt_u_kernel<<<gridCvtU, blk, 0, stream>>>((const float4*)gemb, fgB1);

    // ---- rating channels ----
    for (int c = 0; c < 5; ++c) {
        cvt_rating_kernel<<<gridCvtN, blk, 0, stream>>>(
            (const float4*)(rue + (size_t)c * UU * DD),
            (const float4*)(rie + (size_t)c * II * DD), tblB);
        spmm4_kernel<0><<<gridN, blk, 0, stream>>>(rowptr, c * NN, edata, tblB,
                                                   nullptr, nullptr, AtmpB, nullptr, nullptr, NN);
        spmm4_kernel<1><<<gridN, blk, 0, stream>>>(rowptr, c * NN, edata, AtmpB,
                                                   AtmpB, vvec,
                                                   (uint2*)(chanMean + (size_t)c * NN * DD),
                                                   nullptr, wrat + (size_t)c * NN, NN);
    }

    // ---- attention fuse (rating) ----
    mix5_kernel<<<gridI, blk, 0, stream>>>(chanMean, wrat, UU, II, II, oIS, oMI);
    mix5_kernel<<<gridU, blk, 0, stream>>>(chanMean, wrat, 0, UU, UU, oUS, mixedRU);

    // ---- social: friend ----
    spmm4_kernel<2><<<gridU, blk, 0, stream>>>(rowptr, ROW_S0, edata, fgB0,
                                               nullptr, nullptr, socL1B, nullptr, nullptr, UU);
    spmm4_kernel<3><<<gridU, blk, 0, stream>>>(rowptr, ROW_S0, edata, socL1B,
                                               socL1B, nullptr, nullptr, (float4*)socM0, nullptr, UU);
    // ---- social: group ----
    spmm4_kernel<2><<<gridU, blk, 0, stream>>>(rowptr, ROW_S0 + UU, edata, fgB1,
                                               nullptr, nullptr, socL1B, nullptr, nullptr, UU);
    spmm4_kernel<3><<<gridU, blk, 0, stream>>>(rowptr, ROW_S0 + UU, edata, socL1B,
                                               socL1B, nullptr, nullptr, (float4*)socM1, nullptr, UU);

    // ---- social fuse + adaptive combine ----
    social_mix_final_kernel<<<gridU, blk, 0, stream>>>(socM0, socM1, vvec + 2 * DD,
                                                       mixedRU, adapt, oSS, oMU);
}

// Round 5
// 985.557 us; speedup vs baseline: 3.3740x; 1.0235x over previous
//
#include <hip/hip_runtime.h>
#include <hip/hip_bf16.h>

#define UU 60000
#define II 90000
#define DD 64
#define NN 150000
#define NNZC 1000000
#define NTOT 7000000
#define MTOT 870000           // 5*NN + 2*UU
#define ROW_S0 750000         // start of social rows (5*NN)
#define NBR 733               // rating buckets (1024 rows each)
#define NBS 313               // social buckets (384 rows each)
#define NBCK 1046
#define CAPE 8192             // staging slots per bucket (+16 sigma)
#define ACHUNK 8192           // edges per phase-A block

__device__ __forceinline__ float wave_sum(float x) {
#pragma unroll
    for (int m = 32; m >= 1; m >>= 1) x += __shfl_xor(x, m, 64);
    return x;
}

__device__ __forceinline__ int wave_incl_scan(int x) {
    int lane = threadIdx.x & 63;
#pragma unroll
    for (int d = 1; d < 64; d <<= 1) {
        int y = __shfl_up(x, d, 64);
        if (lane >= d) x += y;
    }
    return x;
}

__device__ int block_incl_scan(int x, int* lds) {
    int wid = threadIdx.x >> 6, lane = threadIdx.x & 63;
    int ws_ = wave_incl_scan(x);
    if (lane == 63) lds[wid] = ws_;
    __syncthreads();
    int off = 0;
    for (int w = 0; w < wid; ++w) off += lds[w];
    __syncthreads();
    return ws_ + off;
}

__device__ __forceinline__ float2 unpack_bf16x2(unsigned p) {
    float2 r;
    r.x = __uint_as_float(p << 16);
    r.y = __uint_as_float(p & 0xffff0000u);
    return r;
}

__device__ __forceinline__ unsigned pack_bf16x2(float a, float b) {
    __hip_bfloat162 h = __float22bfloat162_rn(make_float2(a, b));
    return *(unsigned*)&h;
}

__device__ __forceinline__ uint2 pack4(float4 m) {
    return make_uint2(pack_bf16x2(m.x, m.y), pack_bf16x2(m.z, m.w));
}

__device__ __forceinline__ float4 unpack4(uint2 p) {
    float2 a = unpack_bf16x2(p.x), b = unpack_bf16x2(p.y);
    return make_float4(a.x, a.y, b.x, b.y);
}

__device__ __forceinline__ void qred(float4& a) {
    a.x += __shfl_xor(a.x, 16, 64); a.y += __shfl_xor(a.y, 16, 64);
    a.z += __shfl_xor(a.z, 16, 64); a.w += __shfl_xor(a.w, 16, 64);
    a.x += __shfl_xor(a.x, 32, 64); a.y += __shfl_xor(a.y, 32, 64);
    a.z += __shfl_xor(a.z, 32, 64); a.w += __shfl_xor(a.w, 32, 64);
}

__device__ __forceinline__ int bid_of(int grow) {
    return (grow < ROW_S0) ? (grow >> 10) : NBR + (grow - ROW_S0) / 384;
}

__device__ __forceinline__ int decode_row(int e, const int* rR, const int* fR, const int* gR) {
    if (e < 5 * NNZC) return (e / NNZC) * NN + rR[e];
    if (e < 6 * NNZC) return ROW_S0 + fR[e - 5 * NNZC];
    return ROW_S0 + UU + gR[e - 6 * NNZC];
}

__global__ void att_vec_kernel(const float* __restrict__ au, const float* __restrict__ Mu,
                               const float* __restrict__ ai, const float* __restrict__ Mi,
                               const float* __restrict__ as_, const float* __restrict__ Ms,
                               float* __restrict__ v) {
    int d = threadIdx.x;  // 64 threads
    float su = 0.f, si = 0.f, ss = 0.f;
    for (int e = 0; e < DD; ++e) {
        su += au[e] * Mu[e * DD + d];
        si += ai[e] * Mi[e * DD + d];
        ss += as_[e] * Ms[e * DD + d];
    }
    v[d] = su;
    v[DD + d] = si;
    v[2 * DD + d] = ss;
}

// Phase A: bin edges into fixed-capacity bucket staging regions (b*CAPE).
// Entry = (lrow<<18 | col, f32 val). Block-local LDS counts -> one global
// reservation per (bucket, block).
__global__ __launch_bounds__(256) void phaseA_kernel(
        const int* __restrict__ rR, const int* __restrict__ rC, const float* __restrict__ rV,
        const int* __restrict__ fR, const int* __restrict__ fC, const float* __restrict__ fV,
        const int* __restrict__ gR, const int* __restrict__ gC, const float* __restrict__ gV,
        int* __restrict__ bCur, uint2* __restrict__ ecv) {
    __shared__ int lcnt[NBCK];
    __shared__ int lbase[NBCK];
    int cbase = blockIdx.x * ACHUNK;
    if (cbase >= NTOT) return;
    int eEnd = min(cbase + ACHUNK, NTOT);
    for (int b = threadIdx.x; b < NBCK; b += 256) lcnt[b] = 0;
    __syncthreads();
    // pass 1: count buckets
    for (int e = cbase + threadIdx.x; e < eEnd; e += 256)
        atomicAdd(&lcnt[bid_of(decode_row(e, rR, fR, gR))], 1);
    __syncthreads();
    // pass 2: reserve staging space
    for (int b = threadIdx.x; b < NBCK; b += 256) {
        int n = lcnt[b];
        lbase[b] = n ? atomicAdd(&bCur[b], n) : 0;
    }
    __syncthreads();
    for (int b = threadIdx.x; b < NBCK; b += 256) lcnt[b] = 0;
    __syncthreads();
    // pass 3: decode fully + write
    for (int e = cbase + threadIdx.x; e < eEnd; e += 256) {
        int grow, c; float v;
        if (e < 5 * NNZC) { grow = (e / NNZC) * NN + rR[e]; c = rC[e]; v = rV[e]; }
        else if (e < 6 * NNZC) { int k = e - 5 * NNZC; grow = ROW_S0 + fR[k]; c = fC[k]; v = fV[k]; }
        else { int k = e - 6 * NNZC; grow = ROW_S0 + UU + gR[k]; c = gC[k]; v = gV[k]; }
        int b = bid_of(grow);
        int lrow = (grow < ROW_S0) ? (grow & 1023) : ((grow - ROW_S0) % 384);
        int pos = lbase[b] + atomicAdd(&lcnt[b], 1);
        if (pos < CAPE)
            ecv[(size_t)b * CAPE + pos] =
                make_uint2(((unsigned)lrow << 18) | (unsigned)c, __float_as_uint(v));
    }
}

// single-block exclusive scan of bucket counts -> bStart; sentinel rowptr[MTOT]
__global__ void bscan_kernel(const int* __restrict__ bCur, int* __restrict__ bStart,
                             int* __restrict__ rowptr) {
    __shared__ int lds8[8];
    __shared__ int sOff;
    if (threadIdx.x == 0) sOff = 0;
    __syncthreads();
    for (int base = 0; base < NBCK; base += 256) {
        int i = base + threadIdx.x;
        int v = (i < NBCK) ? bCur[i] : 0;
        int incl = block_incl_scan(v, lds8);
        if (i < NBCK) bStart[i] = sOff + incl - v;
        __syncthreads();
        if (threadIdx.x == 255) sOff += incl;
        __syncthreads();
    }
    if (threadIdx.x == 0) { bStart[NBCK] = sOff; rowptr[MTOT] = sOff; }
}

// Phase B: per-bucket LDS permutation sort -> coalesced edata writes; emits rowptr.
__global__ __launch_bounds__(256) void phaseB_kernel(const int* __restrict__ bStart,
                                                     const int* __restrict__ bCur,
                                                     int* __restrict__ rowptr,
                                                     const uint2* __restrict__ ecv,
                                                     uint2* __restrict__ edata) {
    __shared__ unsigned short perm[CAPE];  // 16 KB
    __shared__ int off[1024];
    __shared__ int lds8[8];
    int b = blockIdx.x;
    int firstRow = (b < NBR) ? (b << 10) : ROW_S0 + (b - NBR) * 384;
    int rowEnd = (b < NBR) ? min((b + 1) << 10, ROW_S0)
                           : min(ROW_S0 + (b - NBR + 1) * 384, MTOT);
    int nRows = rowEnd - firstRow;
    size_t src = (size_t)b * CAPE;
    int dst = bStart[b];
    int count = min(bCur[b], CAPE);
    for (int i = threadIdx.x; i < nRows; i += 256) off[i] = 0;
    __syncthreads();
    // histogram by local row
    for (int i = threadIdx.x; i < count; i += 256)
        atomicAdd(&off[ecv[src + i].x >> 18], 1);
    __syncthreads();
    // scan (4 rows/thread), emit rowptr + exclusive offsets
    int base4 = threadIdx.x * 4;
    int v4[4], s = 0;
#pragma unroll
    for (int k = 0; k < 4; ++k) {
        int i = base4 + k;
        v4[k] = (i < nRows) ? off[i] : 0;
        s += v4[k];
    }
    int incl = block_incl_scan(s, lds8);
    int run = incl - s;
#pragma unroll
    for (int k = 0; k < 4; ++k) {
        int i = base4 + k;
        if (i < nRows) { rowptr[firstRow + i] = dst + run; off[i] = run; }
        run += v4[k];
    }
    __syncthreads();
    // build permutation
    for (int i = threadIdx.x; i < count; i += 256) {
        int pos = atomicAdd(&off[ecv[src + i].x >> 18], 1);
        if (pos < CAPE) perm[pos] = (unsigned short)i;
    }
    __syncthreads();
    // coalesced write via permutation (ecv window is L2-resident)
    for (int i = threadIdx.x; i < count; i += 256) {
        uint2 e = ecv[src + perm[i]];
        edata[dst + i] = make_uint2(e.x & 0x3FFFFu, e.y);
    }
}

// 4 edges in flight per wave; 16 lanes x 4 dims per edge.
// MODE 0: gather f32 split (rue/rie)  -> out bf16 = acc          (rating L1)
// MODE 1: gather bf16 tbl; m=0.5*(acc+self); out bf16; wOut=tanh (rating L2)
// MODE 2: gather f32 (femb/gemb)      -> out bf16 = l2norm(acc)  (social L1)
// MODE 3: gather bf16 tbl -> out f32 = 0.5*(self + l2norm(acc))  (social L2)
template <int MODE>
__global__ __launch_bounds__(256) void spmm4_kernel(
        const int* __restrict__ rowptr, int rowBase,
        const uint2* __restrict__ edata,
        const float* __restrict__ xloF, const float* __restrict__ xhiF,
        const uint2* __restrict__ tblB,
        const uint2* __restrict__ selfB, const float* __restrict__ vvec,
        uint2* __restrict__ outB, float4* __restrict__ outF,
        float* __restrict__ wOut, int nRows) {
    int lane = threadIdx.x & 63;
    int q = lane >> 4;      // quarter: which of 4 concurrent edges
    int h = lane & 15;      // dim group: dims 4h..4h+3
    int row = blockIdx.x * (blockDim.x >> 6) + (threadIdx.x >> 6);
    if (row >= nRows) return;
    int g = rowBase + row;
    int start = rowptr[g], end = rowptr[g + 1];
    float4 acc = make_float4(0.f, 0.f, 0.f, 0.f);
    for (int j0 = start; j0 < end; j0 += 64) {
        uint2 md = make_uint2(0u, 0u);
        if (j0 + lane < end) md = edata[j0 + lane];
        int cnt = min(end - j0, 64);
        for (int j = 0; j < cnt; j += 4) {
            int jj = j + q;
            int c = __shfl((int)md.x, jj, 64);
            float v = __uint_as_float((unsigned)__shfl((int)md.y, jj, 64));
            if (jj >= cnt) { v = 0.f; c = 0; }
            float4 xv;
            if (MODE == 0) {
                const float* src = (c < UU) ? (xloF + (size_t)c * DD)
                                            : (xhiF + (size_t)(c - UU) * DD);
                xv = *(const float4*)(src + 4 * h);
            } else if (MODE == 2) {
                xv = *(const float4*)(xloF + (size_t)c * DD + 4 * h);
            } else {
                xv = unpack4(tblB[(size_t)c * 16 + h]);
            }
            acc.x += v * xv.x; acc.y += v * xv.y;
            acc.z += v * xv.z; acc.w += v * xv.w;
        }
    }
    qred(acc);  // combine quarters; every lane has full sums for its 4 dims

    size_t ro = (size_t)row * 16 + h;
    if (MODE == 0) {
        if (q == 0) outB[ro] = pack4(acc);
    } else if (MODE == 1) {
        float4 sv = unpack4(selfB[ro]);
        float4 m = make_float4(0.5f * (acc.x + sv.x), 0.5f * (acc.y + sv.y),
                               0.5f * (acc.z + sv.z), 0.5f * (acc.w + sv.w));
        if (q == 0) outB[ro] = pack4(m);
        const float* vv = (row < UU) ? vvec : (vvec + DD);
        float4 vw = *(const float4*)(vv + 4 * h);
        float partial = m.x * vw.x + m.y * vw.y + m.z * vw.z + m.w * vw.w;
        float sdot = wave_sum(partial) * 0.25f;
        if (lane == 0) wOut[row] = tanhf(sdot);
    } else if (MODE == 2) {
        float n2 = wave_sum(acc.x * acc.x + acc.y * acc.y + acc.z * acc.z + acc.w * acc.w) * 0.25f;
        float inv = 1.f / fmaxf(sqrtf(n2), 1e-12f);
        if (q == 0) outB[ro] = pack4(make_float4(acc.x * inv, acc.y * inv, acc.z * inv, acc.w * inv));
    } else {
        float n2 = wave_sum(acc.x * acc.x + acc.y * acc.y + acc.z * acc.z + acc.w * acc.w) * 0.25f;
        float inv = 1.f / fmaxf(sqrtf(n2), 1e-12f);
        float4 sv = unpack4(selfB[ro]);
        if (q == 0)
            outF[ro] = make_float4(0.5f * (sv.x + acc.x * inv), 0.5f * (sv.y + acc.y * inv),
                                   0.5f * (sv.z + acc.z * inv), 0.5f * (sv.w + acc.w * inv));
    }
}

// softmax over 5 channels per row (bf16 channel embeddings)
__global__ void mix5_kernel(const __hip_bfloat16* __restrict__ chanEmb,
                            const float* __restrict__ w,
                            int rowOff, int nRows, int scoreStride,
                            float* __restrict__ scoresOut, float* __restrict__ mixedOut) {
    int lane = threadIdx.x & 63;
    int n = blockIdx.x * (blockDim.x >> 6) + (threadIdx.x >> 6);
    if (n >= nRows) return;
    int gn = n + rowOff;
    float sw[5];
    float mx = -2.0f;
#pragma unroll
    for (int c = 0; c < 5; ++c) {
        sw[c] = w[(size_t)c * NN + gn];
        mx = fmaxf(mx, sw[c]);
    }
    float sum = 0.f;
#pragma unroll
    for (int c = 0; c < 5; ++c) {
        sw[c] = expf(sw[c] - mx);
        sum += sw[c];
    }
    float inv = 1.0f / sum;
    float acc = 0.f;
#pragma unroll
    for (int c = 0; c < 5; ++c) {
        float s = sw[c] * inv;
        if (lane == c) scoresOut[(size_t)c * scoreStride + n] = s;
        acc += s * __bfloat162float(chanEmb[((size_t)c * NN + gn) * DD + lane]);
    }
    mixedOut[(size_t)n * DD + lane] = acc;
}

// social 2-channel softmax fuse + adaptive final combine
__global__ void social_mix_final_kernel(const float* __restrict__ e0, const float* __restrict__ e1,
                                        const float* __restrict__ vs,
                                        const float* __restrict__ mixedRU,
                                        const float* __restrict__ adaptive,
                                        float* __restrict__ scoresOut,
                                        float* __restrict__ outMU) {
    int lane = threadIdx.x & 63;
    int n = blockIdx.x * (blockDim.x >> 6) + (threadIdx.x >> 6);
    if (n >= UU) return;
    size_t idx = (size_t)n * DD + lane;
    float a = e0[idx];
    float b = e1[idx];
    float v = vs[lane];
    float w0 = tanhf(wave_sum(a * v));
    float w1 = tanhf(wave_sum(b * v));
    float mx = fmaxf(w0, w1);
    float x0 = expf(w0 - mx);
    float x1 = expf(w1 - mx);
    float inv = 1.0f / (x0 + x1);
    float s0 = x0 * inv;
    float s1 = x1 * inv;
    if (lane == 0) {
        scoresOut[n] = s0;
        scoresOut[UU + n] = s1;
    }
    float ms = s0 * a + s1 * b;
    float mru = mixedRU[idx];
    float num = wave_sum(mru * ms);
    float na = sqrtf(wave_sum(mru * mru));
    float nb = sqrtf(wave_sum(ms * ms));
    float denom = fmaxf(na, 1e-8f) * fmaxf(nb, 1e-8f);
    float sim = num / denom;
    float rate = 1.0f / (2.0f + fmaxf(sim, 0.f) * adaptive[n]);
    outMU[idx] = mru + ms * rate;
}

extern "C" void kernel_launch(void* const* d_in, const int* in_sizes, int n_in,
                              void* d_out, int out_size, void* d_ws, size_t ws_size,
                              hipStream_t stream) {
    const int* r_rows = (const int*)d_in[0];
    const int* r_cols = (const int*)d_in[1];
    const float* r_vals = (const float*)d_in[2];
    const int* f_rows = (const int*)d_in[3];
    const int* f_cols = (const int*)d_in[4];
    const float* f_vals = (const float*)d_in[5];
    const int* g_rows = (const int*)d_in[6];
    const int* g_cols = (const int*)d_in[7];
    const float* g_vals = (const float*)d_in[8];
    const float* rue = (const float*)d_in[9];
    const float* rie = (const float*)d_in[10];
    const float* femb = (const float*)d_in[11];
    const float* gemb = (const float*)d_in[12];
    const float* uaw = (const float*)d_in[13];
    const float* uamw = (const float*)d_in[14];
    const float* iaw = (const float*)d_in[15];
    const float* iamw = (const float*)d_in[16];
    const float* saw = (const float*)d_in[17];
    const float* samw = (const float*)d_in[18];
    const float* adapt = (const float*)d_in[19];

    // ws layout (float units) — total ≈ 56.76M floats ≈ 227 MB
    float* ws = (float*)d_ws;
    size_t o = 0;
    int* rowptr = (int*)(ws + o); o += 870016;        // MTOT+1
    int* bStart = (int*)(ws + o); o += 2048;          // NBCK+1
    int* bCur   = (int*)(ws + o); o += 2048;
    float* Ebase = ws + o; o += (size_t)NBCK * CAPE * 2;   // ecv staging (68.6 MB)
    float* edF   = ws + o; o += 14000000;             // edata (56 MB)
    float* cmBase = ws + o; o += 24000000;            // chanMean bf16 (96 MB)
    float* wrat = ws + o; o += 750016;
    float* vvec = ws + o; o += 192;

    uint2* ecv = (uint2*)Ebase;
    uint2* edata = (uint2*)edF;
    // post-build aliases in the ecv region (dead after phaseB):
    uint2* AtmpB = (uint2*)Ebase;                     // NN*16 uint2 (19.2 MB)
    float* mixedRU = Ebase + 4800000;                 // UU*64 f32
    float* socM0 = Ebase + 8640000;                   // UU*64 f32
    float* socM1 = Ebase + 12480000;                  // UU*64 f32
    // chanMean region aliases (dead after mix5):
    __hip_bfloat16* chanMean = (__hip_bfloat16*)cmBase;
    uint2* socL1B = (uint2*)cmBase;                   // UU*16 uint2

    float* out = (float*)d_out;
    float* oUS = out;
    float* oIS = oUS + (size_t)5 * UU;
    float* oSS = oIS + (size_t)5 * II;
    float* oMU = oSS + (size_t)2 * UU;
    float* oMI = oMU + (size_t)UU * DD;

    const dim3 blk(256);
    const int gridN = (NN + 3) / 4;
    const int gridU = (UU + 3) / 4;
    const int gridI = (II + 3) / 4;
    const int gridA = (NTOT + ACHUNK - 1) / ACHUNK;   // 855

    att_vec_kernel<<<1, 64, 0, stream>>>(uaw, uamw, iaw, iamw, saw, samw, vvec);

    // ---- build sorted CSR for all 7 graphs ----
    hipMemsetAsync(bCur, 0, NBCK * sizeof(int), stream);
    phaseA_kernel<<<gridA, blk, 0, stream>>>(r_rows, r_cols, r_vals,
                                             f_rows, f_cols, f_vals,
                                             g_rows, g_cols, g_vals, bCur, ecv);
    bscan_kernel<<<1, blk, 0, stream>>>(bCur, bStart, rowptr);
    phaseB_kernel<<<NBCK, blk, 0, stream>>>(bStart, bCur, rowptr, ecv, edata);

    // ---- rating channels (f32 direct gather, no cvt) ----
    for (int c = 0; c < 5; ++c) {
        spmm4_kernel<0><<<gridN, blk, 0, stream>>>(
            rowptr, c * NN, edata,
            rue + (size_t)c * UU * DD, rie + (size_t)c * II * DD, nullptr,
            nullptr, nullptr, AtmpB, nullptr, nullptr, NN);
        spmm4_kernel<1><<<gridN, blk, 0, stream>>>(
            rowptr, c * NN, edata,
            nullptr, nullptr, AtmpB, AtmpB, vvec,
            (uint2*)(chanMean + (size_t)c * NN * DD), nullptr, wrat + (size_t)c * NN, NN);
    }

    // ---- attention fuse (rating) ----
    mix5_kernel<<<gridI, blk, 0, stream>>>(chanMean, wrat, UU, II, II, oIS, oMI);
    mix5_kernel<<<gridU, blk, 0, stream>>>(chanMean, wrat, 0, UU, UU, oUS, mixedRU);

    // ---- social: friend ----
    spmm4_kernel<2><<<gridU, blk, 0, stream>>>(rowptr, ROW_S0, edata, femb, femb, nullptr,
                                               nullptr, nullptr, socL1B, nullptr, nullptr, UU);
    spmm4_kernel<3><<<gridU, blk, 0, stream>>>(rowptr, ROW_S0, edata, nullptr, nullptr, socL1B,
                                               socL1B, nullptr, nullptr, (float4*)socM0, nullptr, UU);
    // ---- social: group ----
    spmm4_kernel<2><<<gridU, blk, 0, stream>>>(rowptr, ROW_S0 + UU, edata, gemb, gemb, nullptr,
                                               nullptr, nullptr, socL1B, nullptr, nullptr, UU);
    spmm4_kernel<3><<<gridU, blk, 0, stream>>>(rowptr, ROW_S0 + UU, edata, nullptr, nullptr, socL1B,
                                               socL1B, nullptr, nullptr, (float4*)socM1, nullptr, UU);

    // ---- social fuse + adaptive combine ----
    social_mix_final_kernel<<<gridU, blk, 0, stream>>>(socM0, socM1, vvec + 2 * DD,
                                                       mixedRU, adapt, oSS, oMU);
}

// Round 6
// 783.009 us; speedup vs baseline: 4.2467x; 1.2587x over previous
//
#include <hip/hip_runtime.h>
#include <hip/hip_bf16.h>

#define UU 60000
#define II 90000
#define DD 64
#define NN 150000
#define NNZC 1000000
#define NTOT 7000000
#define MTOT 870000           // 5*NN + 2*UU
#define ROW_S0 750000         // start of social rows (5*NN)
#define NBR 733               // rating buckets (1024 rows each)
#define NBCK 1046             // + 313 social buckets (384 rows each)
#define CAPE 8192             // phaseB LDS sort capacity
#define ACH 16384             // edges per partition block
#define GRID_A 428            // ceil(NTOT/ACH)

__device__ __forceinline__ int wave_incl_scan(int x) {
    int lane = threadIdx.x & 63;
#pragma unroll
    for (int d = 1; d < 64; d <<= 1) {
        int y = __shfl_up(x, d, 64);
        if (lane >= d) x += y;
    }
    return x;
}

__device__ int block_incl_scan(int x, int* lds) {
    int wid = threadIdx.x >> 6, lane = threadIdx.x & 63;
    int ws_ = wave_incl_scan(x);
    if (lane == 63) lds[wid] = ws_;
    __syncthreads();
    int off = 0;
    for (int w = 0; w < wid; ++w) off += lds[w];
    __syncthreads();
    return ws_ + off;
}

__device__ __forceinline__ float2 unpack_bf16x2(unsigned p) {
    float2 r;
    r.x = __uint_as_float(p << 16);
    r.y = __uint_as_float(p & 0xffff0000u);
    return r;
}

__device__ __forceinline__ unsigned pack_bf16x2(float a, float b) {
    __hip_bfloat162 h = __float22bfloat162_rn(make_float2(a, b));
    return *(unsigned*)&h;
}

__device__ __forceinline__ uint2 pack4(float4 m) {
    return make_uint2(pack_bf16x2(m.x, m.y), pack_bf16x2(m.z, m.w));
}

__device__ __forceinline__ float4 unpack4(uint2 p) {
    float2 a = unpack_bf16x2(p.x), b = unpack_bf16x2(p.y);
    return make_float4(a.x, a.y, b.x, b.y);
}

__device__ __forceinline__ int bid_of(int grow) {
    return (grow < ROW_S0) ? (grow >> 10) : NBR + (grow - ROW_S0) / 384;
}

__device__ __forceinline__ int decode_row(int e, const int* rR, const int* fR, const int* gR) {
    if (e < 5 * NNZC) return (e / NNZC) * NN + rR[e];
    if (e < 6 * NNZC) return ROW_S0 + fR[e - 5 * NNZC];
    return ROW_S0 + UU + gR[e - 6 * NNZC];
}

__global__ void att_vec_kernel(const float* __restrict__ au, const float* __restrict__ Mu,
                               const float* __restrict__ ai, const float* __restrict__ Mi,
                               const float* __restrict__ as_, const float* __restrict__ Ms,
                               float* __restrict__ v) {
    int d = threadIdx.x;  // 64 threads
    float su = 0.f, si = 0.f, ss = 0.f;
    for (int e = 0; e < DD; ++e) {
        su += au[e] * Mu[e * DD + d];
        si += ai[e] * Mi[e * DD + d];
        ss += as_[e] * Ms[e * DD + d];
    }
    v[d] = su;
    v[DD + d] = si;
    v[2 * DD + d] = ss;
}

// per-block bucket histogram -> gHistT[bucket][block] (1.79 MB, L2-resident)
__global__ __launch_bounds__(256) void pa_count_kernel(const int* __restrict__ rR,
                                                       const int* __restrict__ fR,
                                                       const int* __restrict__ gR,
                                                       int* __restrict__ gHistT) {
    __shared__ int lcnt[NBCK];
    int k = blockIdx.x;
    int cbase = k * ACH;
    int eEnd = min(cbase + ACH, NTOT);
    for (int b = threadIdx.x; b < NBCK; b += 256) lcnt[b] = 0;
    __syncthreads();
    for (int e = cbase + threadIdx.x; e < eEnd; e += 256)
        atomicAdd(&lcnt[bid_of(decode_row(e, rR, fR, gR))], 1);
    __syncthreads();
    for (int b = threadIdx.x; b < NBCK; b += 256)
        gHistT[(size_t)b * GRID_A + k] = lcnt[b];
}

// one wave per bucket: in-place exclusive prefix over its 428 block counts + total
__global__ void kprefix_kernel(int* __restrict__ gHistT, int* __restrict__ bTot) {
    int b = blockIdx.x * (blockDim.x >> 6) + (threadIdx.x >> 6);
    if (b >= NBCK) return;
    int lane = threadIdx.x & 63;
    int* g = gHistT + (size_t)b * GRID_A;
    int carry = 0;
    for (int c0 = 0; c0 < GRID_A; c0 += 64) {
        int idx = c0 + lane;
        int v = (idx < GRID_A) ? g[idx] : 0;
        int incl = wave_incl_scan(v);
        if (idx < GRID_A) g[idx] = carry + incl - v;
        carry += __shfl(incl, 63, 64);
    }
    if (lane == 0) bTot[b] = carry;
}

// single-block exclusive scan of bucket totals -> bStart; sentinels
__global__ void bscan_kernel(const int* __restrict__ bTot, int* __restrict__ bStart,
                             int* __restrict__ rowptr) {
    __shared__ int lds8[8];
    __shared__ int sOff;
    if (threadIdx.x == 0) sOff = 0;
    __syncthreads();
    for (int base = 0; base < NBCK; base += 256) {
        int i = base + threadIdx.x;
        int v = (i < NBCK) ? bTot[i] : 0;
        int incl = block_incl_scan(v, lds8);
        if (i < NBCK) bStart[i] = sOff + incl - v;
        __syncthreads();
        if (threadIdx.x == 255) sOff += incl;
        __syncthreads();
    }
    if (threadIdx.x == 0) { bStart[NBCK] = sOff; rowptr[MTOT] = sOff; }
}

// single pass: decode + write to exact compact bucket-major slot
__global__ __launch_bounds__(256) void pa_scatter_kernel(
        const int* __restrict__ rR, const int* __restrict__ rC, const float* __restrict__ rV,
        const int* __restrict__ fR, const int* __restrict__ fC, const float* __restrict__ fV,
        const int* __restrict__ gR, const int* __restrict__ gC, const float* __restrict__ gV,
        const int* __restrict__ bStart, const int* __restrict__ gHistT,
        uint2* __restrict__ ecv) {
    __shared__ int lcur[NBCK];
    int k = blockIdx.x;
    int cbase = k * ACH;
    int eEnd = min(cbase + ACH, NTOT);
    for (int b = threadIdx.x; b < NBCK; b += 256)
        lcur[b] = bStart[b] + gHistT[(size_t)b * GRID_A + k];
    __syncthreads();
    for (int e = cbase + threadIdx.x; e < eEnd; e += 256) {
        int grow, c; float v;
        if (e < 5 * NNZC) { grow = (e / NNZC) * NN + rR[e]; c = rC[e]; v = rV[e]; }
        else if (e < 6 * NNZC) { int kk = e - 5 * NNZC; grow = ROW_S0 + fR[kk]; c = fC[kk]; v = fV[kk]; }
        else { int kk = e - 6 * NNZC; grow = ROW_S0 + UU + gR[kk]; c = gC[kk]; v = gV[kk]; }
        int b = bid_of(grow);
        int lrow = (grow < ROW_S0) ? (grow & 1023) : ((grow - ROW_S0) % 384);
        int pos = atomicAdd(&lcur[b], 1);
        ecv[pos] = make_uint2(((unsigned)lrow << 18) | (unsigned)c, __float_as_uint(v));
    }
}

// per-bucket LDS permutation sort -> row-sorted edata (coalesced); emits rowptr
__global__ __launch_bounds__(256) void phaseB_kernel(const int* __restrict__ bStart,
                                                     int* __restrict__ rowptr,
                                                     const uint2* __restrict__ ecv,
                                                     uint2* __restrict__ edata) {
    __shared__ unsigned short perm[CAPE];  // 16 KB
    __shared__ int off[1024];
    __shared__ int lds8[8];
    int b = blockIdx.x;
    int firstRow = (b < NBR) ? (b << 10) : ROW_S0 + (b - NBR) * 384;
    int rowEnd = (b < NBR) ? min((b + 1) << 10, ROW_S0)
                           : min(ROW_S0 + (b - NBR + 1) * 384, MTOT);
    int nRows = rowEnd - firstRow;
    int dst = bStart[b];
    int count = bStart[b + 1] - dst;
    for (int i = threadIdx.x; i < nRows; i += 256) off[i] = 0;
    __syncthreads();
    for (int i = threadIdx.x; i < count; i += 256)
        atomicAdd(&off[ecv[dst + i].x >> 18], 1);
    __syncthreads();
    int base4 = threadIdx.x * 4;
    int v4[4], s = 0;
#pragma unroll
    for (int kk = 0; kk < 4; ++kk) {
        int i = base4 + kk;
        v4[kk] = (i < nRows) ? off[i] : 0;
        s += v4[kk];
    }
    int incl = block_incl_scan(s, lds8);
    int run = incl - s;
#pragma unroll
    for (int kk = 0; kk < 4; ++kk) {
        int i = base4 + kk;
        if (i < nRows) { rowptr[firstRow + i] = dst + run; off[i] = run; }
        run += v4[kk];
    }
    __syncthreads();
    if (count <= CAPE) {
        for (int i = threadIdx.x; i < count; i += 256) {
            int pos = atomicAdd(&off[ecv[dst + i].x >> 18], 1);
            perm[pos] = (unsigned short)i;
        }
        __syncthreads();
        for (int i = threadIdx.x; i < count; i += 256) {
            uint2 e = ecv[dst + perm[i]];
            edata[dst + i] = make_uint2(e.x & 0x3FFFFu, e.y);
        }
    } else {
        for (int i = threadIdx.x; i < count; i += 256) {
            uint2 e = ecv[dst + i];
            int pos = atomicAdd(&off[e.x >> 18], 1);
            edata[dst + pos] = make_uint2(e.x & 0x3FFFFu, e.y);
        }
    }
}

// 16 lanes per row, 4 rows per wave; each lane owns 4 dims end-to-end (no reduction).
// MODE 0: gather f32 split (rue/rie)  -> out bf16 = acc          (rating L1)
// MODE 1: gather bf16 tbl; m=0.5*(acc+self); out bf16; wOut=tanh (rating L2)
// MODE 2: gather f32 (femb/gemb)      -> out bf16 = l2norm(acc)  (social L1)
// MODE 3: gather bf16 tbl -> out f32 = 0.5*(self + l2norm(acc))  (social L2)
template <int MODE>
__global__ __launch_bounds__(256) void spmm_kernel(
        const int* __restrict__ rowptr, int rowBase,
        const uint2* __restrict__ edata,
        const float* __restrict__ xloF, const float* __restrict__ xhiF,
        const uint2* __restrict__ tblB,
        const uint2* __restrict__ selfB, const float* __restrict__ vvec,
        uint2* __restrict__ outB, float4* __restrict__ outF,
        float* __restrict__ wOut, int nRows) {
    int lane = threadIdx.x & 63;
    int l16 = lane & 15;
    int grpBase = lane & 48;
    int wid = blockIdx.x * (blockDim.x >> 6) + (threadIdx.x >> 6);
    int row = wid * 4 + (lane >> 4);
    bool active = row < nRows;
    int g = rowBase + row;
    int start = active ? rowptr[g] : 0;
    int end = active ? rowptr[g + 1] : 0;
    float4 acc = make_float4(0.f, 0.f, 0.f, 0.f);
    for (int j0 = start; j0 < end; j0 += 16) {
        uint2 md = make_uint2(0u, 0u);
        if (j0 + l16 < end) md = edata[j0 + l16];
        int cnt = min(end - j0, 16);
        for (int j = 0; j < cnt; ++j) {
            int c = __shfl((int)md.x, grpBase + j, 64);
            float v = __uint_as_float((unsigned)__shfl((int)md.y, grpBase + j, 64));
            float4 xv;
            if (MODE == 0) {
                const float* src = (c < UU) ? (xloF + (size_t)c * DD)
                                            : (xhiF + (size_t)(c - UU) * DD);
                xv = *(const float4*)(src + 4 * l16);
            } else if (MODE == 2) {
                xv = *(const float4*)(xloF + (size_t)c * DD + 4 * l16);
            } else {
                xv = unpack4(tblB[(size_t)c * 16 + l16]);
            }
            acc.x += v * xv.x; acc.y += v * xv.y;
            acc.z += v * xv.z; acc.w += v * xv.w;
        }
    }
    if (!active) return;
    size_t ro = (size_t)row * 16 + l16;
    if (MODE == 0) {
        outB[ro] = pack4(acc);
    } else if (MODE == 1) {
        float4 sv = unpack4(selfB[ro]);
        float4 m = make_float4(0.5f * (acc.x + sv.x), 0.5f * (acc.y + sv.y),
                               0.5f * (acc.z + sv.z), 0.5f * (acc.w + sv.w));
        outB[ro] = pack4(m);
        const float* vv = (row < UU) ? vvec : (vvec + DD);
        float4 vw = *(const float4*)(vv + 4 * l16);
        float p = m.x * vw.x + m.y * vw.y + m.z * vw.z + m.w * vw.w;
        p += __shfl_xor(p, 1, 64); p += __shfl_xor(p, 2, 64);
        p += __shfl_xor(p, 4, 64); p += __shfl_xor(p, 8, 64);
        if (l16 == 0) wOut[row] = tanhf(p);
    } else if (MODE == 2) {
        float n2 = acc.x * acc.x + acc.y * acc.y + acc.z * acc.z + acc.w * acc.w;
        n2 += __shfl_xor(n2, 1, 64); n2 += __shfl_xor(n2, 2, 64);
        n2 += __shfl_xor(n2, 4, 64); n2 += __shfl_xor(n2, 8, 64);
        float inv = 1.f / fmaxf(sqrtf(n2), 1e-12f);
        outB[ro] = pack4(make_float4(acc.x * inv, acc.y * inv, acc.z * inv, acc.w * inv));
    } else {
        float n2 = acc.x * acc.x + acc.y * acc.y + acc.z * acc.z + acc.w * acc.w;
        n2 += __shfl_xor(n2, 1, 64); n2 += __shfl_xor(n2, 2, 64);
        n2 += __shfl_xor(n2, 4, 64); n2 += __shfl_xor(n2, 8, 64);
        float inv = 1.f / fmaxf(sqrtf(n2), 1e-12f);
        float4 sv = unpack4(selfB[ro]);
        outF[ro] = make_float4(0.5f * (sv.x + acc.x * inv), 0.5f * (sv.y + acc.y * inv),
                               0.5f * (sv.z + acc.z * inv), 0.5f * (sv.w + acc.w * inv));
    }
}

// fused user+item 5-channel softmax mix (wave per row, grid over NN)
__global__ void mix5_kernel(const __hip_bfloat16* __restrict__ chanEmb,
                            const float* __restrict__ w,
                            float* __restrict__ oUS, float* __restrict__ oIS,
                            float* __restrict__ mixedRU, float* __restrict__ oMI) {
    int lane = threadIdx.x & 63;
    int n = blockIdx.x * (blockDim.x >> 6) + (threadIdx.x >> 6);
    if (n >= NN) return;
    float sw[5];
    float mx = -2.0f;
#pragma unroll
    for (int c = 0; c < 5; ++c) {
        sw[c] = w[(size_t)c * NN + n];
        mx = fmaxf(mx, sw[c]);
    }
    float sum = 0.f;
#pragma unroll
    for (int c = 0; c < 5; ++c) {
        sw[c] = expf(sw[c] - mx);
        sum += sw[c];
    }
    float inv = 1.0f / sum;
    float acc = 0.f;
#pragma unroll
    for (int c = 0; c < 5; ++c) {
        sw[c] *= inv;
        acc += sw[c] * __bfloat162float(chanEmb[((size_t)c * NN + n) * DD + lane]);
    }
    if (n < UU) {
#pragma unroll
        for (int c = 0; c < 5; ++c)
            if (lane == c) oUS[(size_t)c * UU + n] = sw[c];
        mixedRU[(size_t)n * DD + lane] = acc;
    } else {
        int m = n - UU;
#pragma unroll
        for (int c = 0; c < 5; ++c)
            if (lane == c) oIS[(size_t)c * II + m] = sw[c];
        oMI[(size_t)m * DD + lane] = acc;
    }
}

// social 2-channel softmax fuse + adaptive final combine
__global__ void social_mix_final_kernel(const float* __restrict__ e0, const float* __restrict__ e1,
                                        const float* __restrict__ vs,
                                        const float* __restrict__ mixedRU,
                                        const float* __restrict__ adaptive,
                                        float* __restrict__ scoresOut,
                                        float* __restrict__ outMU) {
    int lane = threadIdx.x & 63;
    int n = blockIdx.x * (blockDim.x >> 6) + (threadIdx.x >> 6);
    if (n >= UU) return;
    size_t idx = (size_t)n * DD + lane;
    float a = e0[idx];
    float b = e1[idx];
    float v = vs[lane];
    float pa = a * v, pb = b * v, nm = 0.f, na2 = 0.f, nb2 = 0.f;
    float mru = mixedRU[idx];
#pragma unroll
    for (int m = 32; m >= 1; m >>= 1) { pa += __shfl_xor(pa, m, 64); pb += __shfl_xor(pb, m, 64); }
    float w0 = tanhf(pa);
    float w1 = tanhf(pb);
    float mx = fmaxf(w0, w1);
    float x0 = expf(w0 - mx);
    float x1 = expf(w1 - mx);
    float invs = 1.0f / (x0 + x1);
    float s0 = x0 * invs;
    float s1 = x1 * invs;
    if (lane == 0) {
        scoresOut[n] = s0;
        scoresOut[UU + n] = s1;
    }
    float ms = s0 * a + s1 * b;
    nm = mru * ms; na2 = mru * mru; nb2 = ms * ms;
#pragma unroll
    for (int m = 32; m >= 1; m >>= 1) {
        nm += __shfl_xor(nm, m, 64); na2 += __shfl_xor(na2, m, 64); nb2 += __shfl_xor(nb2, m, 64);
    }
    float denom = fmaxf(sqrtf(na2), 1e-8f) * fmaxf(sqrtf(nb2), 1e-8f);
    float sim = nm / denom;
    float rate = 1.0f / (2.0f + fmaxf(sim, 0.f) * adaptive[n]);
    outMU[idx] = mru + ms * rate;
}

extern "C" void kernel_launch(void* const* d_in, const int* in_sizes, int n_in,
                              void* d_out, int out_size, void* d_ws, size_t ws_size,
                              hipStream_t stream) {
    const int* r_rows = (const int*)d_in[0];
    const int* r_cols = (const int*)d_in[1];
    const float* r_vals = (const float*)d_in[2];
    const int* f_rows = (const int*)d_in[3];
    const int* f_cols = (const int*)d_in[4];
    const float* f_vals = (const float*)d_in[5];
    const int* g_rows = (const int*)d_in[6];
    const int* g_cols = (const int*)d_in[7];
    const float* g_vals = (const float*)d_in[8];
    const float* rue = (const float*)d_in[9];
    const float* rie = (const float*)d_in[10];
    const float* femb = (const float*)d_in[11];
    const float* gemb = (const float*)d_in[12];
    const float* uaw = (const float*)d_in[13];
    const float* uamw = (const float*)d_in[14];
    const float* iaw = (const float*)d_in[15];
    const float* iamw = (const float*)d_in[16];
    const float* saw = (const float*)d_in[17];
    const float* samw = (const float*)d_in[18];
    const float* adapt = (const float*)d_in[19];

    // ws layout (float units) — total ≈ 54.1M floats ≈ 216 MB
    float* ws = (float*)d_ws;
    size_t o = 0;
    int* rowptr = (int*)(ws + o); o += 870016;        // MTOT+1
    int* bStart = (int*)(ws + o); o += 2048;          // NBCK+1
    int* bTot   = (int*)(ws + o); o += 2048;
    int* gHistT = (int*)(ws + o); o += 448000;        // [NBCK][GRID_A]
    float* R1 = ws + o; o += 14000000;                // ecv -> AtmpB/mixedRU/socM0/socM1
    float* edF = ws + o; o += 14000000;               // edata
    float* R2 = ws + o; o += 24000000;                // chanMean -> socL1B
    float* wrat = ws + o; o += 750016;
    float* vvec = ws + o; o += 192;

    uint2* ecv = (uint2*)R1;
    uint2* edata = (uint2*)edF;
    // aliases in R1 (ecv dead after phaseB):
    uint2* AtmpB = (uint2*)R1;                        // NN*16 uint2 (4.8M floats)
    float* mixedRU = R1;                              // after rating loop (AtmpB dead at mix5)
    float* socM0 = R1 + 4800000;                      // UU*64 f32
    float* socM1 = R1 + 8640000;                      // UU*64 f32
    // aliases in R2 (chanMean dead after mix5):
    __hip_bfloat16* chanMean = (__hip_bfloat16*)R2;   // 5*NN*64 bf16
    uint2* socL1B = (uint2*)R2;                       // UU*16 uint2

    float* out = (float*)d_out;
    float* oUS = out;
    float* oIS = oUS + (size_t)5 * UU;
    float* oSS = oIS + (size_t)5 * II;
    float* oMU = oSS + (size_t)2 * UU;
    float* oMI = oMU + (size_t)UU * DD;

    const dim3 blk(256);
    const int gridN4 = (NN + 15) / 16;    // 4 rows/wave, 4 waves/block
    const int gridU4 = (UU + 15) / 16;
    const int gridMix = (NN + 3) / 4;     // wave per row
    const int gridFin = (UU + 3) / 4;

    att_vec_kernel<<<1, 64, 0, stream>>>(uaw, uamw, iaw, iamw, saw, samw, vvec);

    // ---- build row-sorted CSR for all 7 graphs ----
    pa_count_kernel<<<GRID_A, blk, 0, stream>>>(r_rows, f_rows, g_rows, gHistT);
    kprefix_kernel<<<(NBCK + 3) / 4, blk, 0, stream>>>(gHistT, bTot);
    bscan_kernel<<<1, blk, 0, stream>>>(bTot, bStart, rowptr);
    pa_scatter_kernel<<<GRID_A, blk, 0, stream>>>(r_rows, r_cols, r_vals,
                                                  f_rows, f_cols, f_vals,
                                                  g_rows, g_cols, g_vals,
                                                  bStart, gHistT, ecv);
    phaseB_kernel<<<NBCK, blk, 0, stream>>>(bStart, rowptr, ecv, edata);

    // ---- rating channels ----
    for (int c = 0; c < 5; ++c) {
        spmm_kernel<0><<<gridN4, blk, 0, stream>>>(
            rowptr, c * NN, edata,
            rue + (size_t)c * UU * DD, rie + (size_t)c * II * DD, nullptr,
            nullptr, nullptr, AtmpB, nullptr, nullptr, NN);
        spmm_kernel<1><<<gridN4, blk, 0, stream>>>(
            rowptr, c * NN, edata,
            nullptr, nullptr, AtmpB, AtmpB, vvec,
            (uint2*)(chanMean + (size_t)c * NN * DD), nullptr, wrat + (size_t)c * NN, NN);
    }

    // ---- attention fuse (rating), user+item in one launch ----
    mix5_kernel<<<gridMix, blk, 0, stream>>>(chanMean, wrat, oUS, oIS, mixedRU, oMI);

    // ---- social: friend ----
    spmm_kernel<2><<<gridU4, blk, 0, stream>>>(rowptr, ROW_S0, edata, femb, nullptr, nullptr,
                                               nullptr, nullptr, socL1B, nullptr, nullptr, UU);
    spmm_kernel<3><<<gridU4, blk, 0, stream>>>(rowptr, ROW_S0, edata, nullptr, nullptr, socL1B,
                                               socL1B, nullptr, nullptr, (float4*)socM0, nullptr, UU);
    // ---- social: group ----
    spmm_kernel<2><<<gridU4, blk, 0, stream>>>(rowptr, ROW_S0 + UU, edata, gemb, nullptr, nullptr,
                                               nullptr, nullptr, socL1B, nullptr, nullptr, UU);
    spmm_kernel<3><<<gridU4, blk, 0, stream>>>(rowptr, ROW_S0 + UU, edata, nullptr, nullptr, socL1B,
                                               socL1B, nullptr, nullptr, (float4*)socM1, nullptr, UU);

    // ---- social fuse + adaptive combine ----
    social_mix_final_kernel<<<gridFin, blk, 0, stream>>>(socM0, socM1, vvec + 2 * DD,
                                                         mixedRU, adapt, oSS, oMU);
}

// Round 7
// 741.986 us; speedup vs baseline: 4.4815x; 1.0553x over previous
//
#include <hip/hip_runtime.h>
#include <hip/hip_bf16.h>

#define UU 60000
#define II 90000
#define DD 64
#define NN 150000
#define NNZC 1000000
#define NTOT 7000000
#define MTOT 870000           // 5*NN + 2*UU
#define ROW_S0 750000         // start of social rows (5*NN)
#define NBR 733               // rating buckets (1024 rows each)
#define NBCK 1046             // + 313 social buckets (384 rows each)
#define CAPE 8192             // phaseB LDS sort capacity
#define ACH 4096              // edges per partition block
#define GRID_A 1709           // ceil(NTOT/ACH)

__device__ __forceinline__ int wave_incl_scan(int x) {
    int lane = threadIdx.x & 63;
#pragma unroll
    for (int d = 1; d < 64; d <<= 1) {
        int y = __shfl_up(x, d, 64);
        if (lane >= d) x += y;
    }
    return x;
}

__device__ int block_incl_scan(int x, int* lds) {
    int wid = threadIdx.x >> 6, lane = threadIdx.x & 63;
    int ws_ = wave_incl_scan(x);
    if (lane == 63) lds[wid] = ws_;
    __syncthreads();
    int off = 0;
    for (int w = 0; w < wid; ++w) off += lds[w];
    __syncthreads();
    return ws_ + off;
}

__device__ __forceinline__ float2 unpack_bf16x2(unsigned p) {
    float2 r;
    r.x = __uint_as_float(p << 16);
    r.y = __uint_as_float(p & 0xffff0000u);
    return r;
}

__device__ __forceinline__ unsigned pack_bf16x2(float a, float b) {
    __hip_bfloat162 h = __float22bfloat162_rn(make_float2(a, b));
    return *(unsigned*)&h;
}

__device__ __forceinline__ uint2 pack4(float4 m) {
    return make_uint2(pack_bf16x2(m.x, m.y), pack_bf16x2(m.z, m.w));
}

__device__ __forceinline__ float4 unpack4(uint2 p) {
    float2 a = unpack_bf16x2(p.x), b = unpack_bf16x2(p.y);
    return make_float4(a.x, a.y, b.x, b.y);
}

__device__ __forceinline__ int bid_of(int grow) {
    return (grow < ROW_S0) ? (grow >> 10) : NBR + (grow - ROW_S0) / 384;
}

__device__ __forceinline__ int decode_row(int e, const int* rR, const int* fR, const int* gR) {
    if (e < 5 * NNZC) return (e / NNZC) * NN + rR[e];
    if (e < 6 * NNZC) return ROW_S0 + fR[e - 5 * NNZC];
    return ROW_S0 + UU + gR[e - 6 * NNZC];
}

__global__ void att_vec_kernel(const float* __restrict__ au, const float* __restrict__ Mu,
                               const float* __restrict__ ai, const float* __restrict__ Mi,
                               const float* __restrict__ as_, const float* __restrict__ Ms,
                               float* __restrict__ v) {
    int d = threadIdx.x;  // 64 threads
    float su = 0.f, si = 0.f, ss = 0.f;
    for (int e = 0; e < DD; ++e) {
        su += au[e] * Mu[e * DD + d];
        si += ai[e] * Mi[e * DD + d];
        ss += as_[e] * Ms[e * DD + d];
    }
    v[d] = su;
    v[DD + d] = si;
    v[2 * DD + d] = ss;
}

// per-block bucket histogram -> gHistT[bucket][block] (7.2 MB, L2-resident)
__global__ __launch_bounds__(256) void pa_count_kernel(const int* __restrict__ rR,
                                                       const int* __restrict__ fR,
                                                       const int* __restrict__ gR,
                                                       int* __restrict__ gHistT) {
    __shared__ int lcnt[NBCK];
    int k = blockIdx.x;
    int cbase = k * ACH;
    int eEnd = min(cbase + ACH, NTOT);
    for (int b = threadIdx.x; b < NBCK; b += 256) lcnt[b] = 0;
    __syncthreads();
    for (int e = cbase + threadIdx.x; e < eEnd; e += 256)
        atomicAdd(&lcnt[bid_of(decode_row(e, rR, fR, gR))], 1);
    __syncthreads();
    for (int b = threadIdx.x; b < NBCK; b += 256)
        gHistT[(size_t)b * GRID_A + k] = lcnt[b];
}

// one wave per bucket: in-place exclusive prefix over its GRID_A block counts + total
__global__ void kprefix_kernel(int* __restrict__ gHistT, int* __restrict__ bTot) {
    int b = blockIdx.x * (blockDim.x >> 6) + (threadIdx.x >> 6);
    if (b >= NBCK) return;
    int lane = threadIdx.x & 63;
    int* g = gHistT + (size_t)b * GRID_A;
    int carry = 0;
    for (int c0 = 0; c0 < GRID_A; c0 += 64) {
        int idx = c0 + lane;
        int v = (idx < GRID_A) ? g[idx] : 0;
        int incl = wave_incl_scan(v);
        if (idx < GRID_A) g[idx] = carry + incl - v;
        carry += __shfl(incl, 63, 64);
    }
    if (lane == 0) bTot[b] = carry;
}

// single-block exclusive scan of bucket totals -> bStart; sentinels
__global__ void bscan_kernel(const int* __restrict__ bTot, int* __restrict__ bStart,
                             int* __restrict__ rowptr) {
    __shared__ int lds8[8];
    __shared__ int sOff;
    if (threadIdx.x == 0) sOff = 0;
    __syncthreads();
    for (int base = 0; base < NBCK; base += 256) {
        int i = base + threadIdx.x;
        int v = (i < NBCK) ? bTot[i] : 0;
        int incl = block_incl_scan(v, lds8);
        if (i < NBCK) bStart[i] = sOff + incl - v;
        __syncthreads();
        if (threadIdx.x == 255) sOff += incl;
        __syncthreads();
    }
    if (threadIdx.x == 0) { bStart[NBCK] = sOff; rowptr[MTOT] = sOff; }
}

// single pass: decode + write to exact compact bucket-major slot
__global__ __launch_bounds__(256) void pa_scatter_kernel(
        const int* __restrict__ rR, const int* __restrict__ rC, const float* __restrict__ rV,
        const int* __restrict__ fR, const int* __restrict__ fC, const float* __restrict__ fV,
        const int* __restrict__ gR, const int* __restrict__ gC, const float* __restrict__ gV,
        const int* __restrict__ bStart, const int* __restrict__ gHistT,
        uint2* __restrict__ ecv) {
    __shared__ int lcur[NBCK];
    int k = blockIdx.x;
    int cbase = k * ACH;
    int eEnd = min(cbase + ACH, NTOT);
    for (int b = threadIdx.x; b < NBCK; b += 256)
        lcur[b] = bStart[b] + gHistT[(size_t)b * GRID_A + k];
    __syncthreads();
    for (int e = cbase + threadIdx.x; e < eEnd; e += 256) {
        int grow, c; float v;
        if (e < 5 * NNZC) { grow = (e / NNZC) * NN + rR[e]; c = rC[e]; v = rV[e]; }
        else if (e < 6 * NNZC) { int kk = e - 5 * NNZC; grow = ROW_S0 + fR[kk]; c = fC[kk]; v = fV[kk]; }
        else { int kk = e - 6 * NNZC; grow = ROW_S0 + UU + gR[kk]; c = gC[kk]; v = gV[kk]; }
        int b = bid_of(grow);
        int lrow = (grow < ROW_S0) ? (grow & 1023) : ((grow - ROW_S0) % 384);
        int pos = atomicAdd(&lcur[b], 1);
        ecv[pos] = make_uint2(((unsigned)lrow << 18) | (unsigned)c, __float_as_uint(v));
    }
}

// per-bucket LDS permutation sort -> row-sorted edata (coalesced); emits rowptr
__global__ __launch_bounds__(256) void phaseB_kernel(const int* __restrict__ bStart,
                                                     int* __restrict__ rowptr,
                                                     const uint2* __restrict__ ecv,
                                                     uint2* __restrict__ edata) {
    __shared__ unsigned short perm[CAPE];  // 16 KB
    __shared__ int off[1024];
    __shared__ int lds8[8];
    int b = blockIdx.x;
    int firstRow = (b < NBR) ? (b << 10) : ROW_S0 + (b - NBR) * 384;
    int rowEnd = (b < NBR) ? min((b + 1) << 10, ROW_S0)
                           : min(ROW_S0 + (b - NBR + 1) * 384, MTOT);
    int nRows = rowEnd - firstRow;
    int dst = bStart[b];
    int count = bStart[b + 1] - dst;
    for (int i = threadIdx.x; i < nRows; i += 256) off[i] = 0;
    __syncthreads();
    for (int i = threadIdx.x; i < count; i += 256)
        atomicAdd(&off[ecv[dst + i].x >> 18], 1);
    __syncthreads();
    int base4 = threadIdx.x * 4;
    int v4[4], s = 0;
#pragma unroll
    for (int kk = 0; kk < 4; ++kk) {
        int i = base4 + kk;
        v4[kk] = (i < nRows) ? off[i] : 0;
        s += v4[kk];
    }
    int incl = block_incl_scan(s, lds8);
    int run = incl - s;
#pragma unroll
    for (int kk = 0; kk < 4; ++kk) {
        int i = base4 + kk;
        if (i < nRows) { rowptr[firstRow + i] = dst + run; off[i] = run; }
        run += v4[kk];
    }
    __syncthreads();
    if (count <= CAPE) {
        for (int i = threadIdx.x; i < count; i += 256) {
            int pos = atomicAdd(&off[ecv[dst + i].x >> 18], 1);
            perm[pos] = (unsigned short)i;
        }
        __syncthreads();
        for (int i = threadIdx.x; i < count; i += 256) {
            uint2 e = ecv[dst + perm[i]];
            edata[dst + i] = make_uint2(e.x & 0x3FFFFu, e.y);
        }
    } else {
        for (int i = threadIdx.x; i < count; i += 256) {
            uint2 e = ecv[dst + i];
            int pos = atomicAdd(&off[e.x >> 18], 1);
            edata[dst + pos] = make_uint2(e.x & 0x3FFFFu, e.y);
        }
    }
}

// 16 lanes per row, 4 rows per wave; lane owns 4 dims end-to-end.
// Inner loop: 4 masked edges per batch -> 4 gathers in flight (MLP).
// MODE 0: gather f32 split (rue/rie)  -> out bf16 = acc          (rating L1)
// MODE 1: gather bf16 tbl; m=0.5*(acc+self); out bf16; wOut=tanh (rating L2)
// MODE 2: gather f32 (femb/gemb)      -> out bf16 = l2norm(acc)  (social L1)
// MODE 3: gather bf16 tbl -> out f32 = 0.5*(self + l2norm(acc))  (social L2)
template <int MODE>
__global__ __launch_bounds__(256) void spmm_kernel(
        const int* __restrict__ rowptr, int rowBase,
        const uint2* __restrict__ edata,
        const float* __restrict__ xloF, const float* __restrict__ xhiF,
        const uint2* __restrict__ tblB,
        const uint2* __restrict__ selfB, const float* __restrict__ vvec,
        uint2* __restrict__ outB, float4* __restrict__ outF,
        float* __restrict__ wOut, int nRows) {
    int lane = threadIdx.x & 63;
    int l16 = lane & 15;
    int grpBase = lane & 48;
    int wid = blockIdx.x * (blockDim.x >> 6) + (threadIdx.x >> 6);
    int row = wid * 4 + (lane >> 4);
    bool active = row < nRows;
    int g = rowBase + row;
    int start = active ? rowptr[g] : 0;
    int end = active ? rowptr[g + 1] : 0;
    float4 acc = make_float4(0.f, 0.f, 0.f, 0.f);
    for (int j0 = start; j0 < end; j0 += 16) {
        uint2 md = make_uint2(0u, 0u);
        if (j0 + l16 < end) md = edata[j0 + l16];
        int cnt = min(end - j0, 16);
        for (int js = 0; js < cnt; js += 4) {
            int cc[4]; float vv[4]; float4 xv[4];
#pragma unroll
            for (int u = 0; u < 4; ++u) {
                int jj = js + u;
                int sl = grpBase + ((jj < cnt) ? jj : 0);
                cc[u] = __shfl((int)md.x, sl, 64);
                float v = __uint_as_float((unsigned)__shfl((int)md.y, sl, 64));
                vv[u] = (jj < cnt) ? v : 0.f;
            }
#pragma unroll
            for (int u = 0; u < 4; ++u) {
                int c = cc[u];
                if (MODE == 0) {
                    const float* src = (c < UU) ? (xloF + (size_t)c * DD)
                                                : (xhiF + (size_t)(c - UU) * DD);
                    xv[u] = *(const float4*)(src + 4 * l16);
                } else if (MODE == 2) {
                    xv[u] = *(const float4*)(xloF + (size_t)c * DD + 4 * l16);
                } else {
                    xv[u] = unpack4(tblB[(size_t)c * 16 + l16]);
                }
            }
#pragma unroll
            for (int u = 0; u < 4; ++u) {
                acc.x += vv[u] * xv[u].x; acc.y += vv[u] * xv[u].y;
                acc.z += vv[u] * xv[u].z; acc.w += vv[u] * xv[u].w;
            }
        }
    }
    if (!active) return;
    size_t ro = (size_t)row * 16 + l16;
    if (MODE == 0) {
        outB[ro] = pack4(acc);
    } else if (MODE == 1) {
        float4 sv = unpack4(selfB[ro]);
        float4 m = make_float4(0.5f * (acc.x + sv.x), 0.5f * (acc.y + sv.y),
                               0.5f * (acc.z + sv.z), 0.5f * (acc.w + sv.w));
        outB[ro] = pack4(m);
        const float* vv = (row < UU) ? vvec : (vvec + DD);
        float4 vw = *(const float4*)(vv + 4 * l16);
        float p = m.x * vw.x + m.y * vw.y + m.z * vw.z + m.w * vw.w;
        p += __shfl_xor(p, 1, 64); p += __shfl_xor(p, 2, 64);
        p += __shfl_xor(p, 4, 64); p += __shfl_xor(p, 8, 64);
        if (l16 == 0) wOut[row] = tanhf(p);
    } else if (MODE == 2) {
        float n2 = acc.x * acc.x + acc.y * acc.y + acc.z * acc.z + acc.w * acc.w;
        n2 += __shfl_xor(n2, 1, 64); n2 += __shfl_xor(n2, 2, 64);
        n2 += __shfl_xor(n2, 4, 64); n2 += __shfl_xor(n2, 8, 64);
        float inv = 1.f / fmaxf(sqrtf(n2), 1e-12f);
        outB[ro] = pack4(make_float4(acc.x * inv, acc.y * inv, acc.z * inv, acc.w * inv));
    } else {
        float n2 = acc.x * acc.x + acc.y * acc.y + acc.z * acc.z + acc.w * acc.w;
        n2 += __shfl_xor(n2, 1, 64); n2 += __shfl_xor(n2, 2, 64);
        n2 += __shfl_xor(n2, 4, 64); n2 += __shfl_xor(n2, 8, 64);
        float inv = 1.f / fmaxf(sqrtf(n2), 1e-12f);
        float4 sv = unpack4(selfB[ro]);
        outF[ro] = make_float4(0.5f * (sv.x + acc.x * inv), 0.5f * (sv.y + acc.y * inv),
                               0.5f * (sv.z + acc.z * inv), 0.5f * (sv.w + acc.w * inv));
    }
}

// fused user+item 5-channel softmax mix (wave per row, grid over NN)
__global__ void mix5_kernel(const __hip_bfloat16* __restrict__ chanEmb,
                            const float* __restrict__ w,
                            float* __restrict__ oUS, float* __restrict__ oIS,
                            float* __restrict__ mixedRU, float* __restrict__ oMI) {
    int lane = threadIdx.x & 63;
    int n = blockIdx.x * (blockDim.x >> 6) + (threadIdx.x >> 6);
    if (n >= NN) return;
    float sw[5];
    float mx = -2.0f;
#pragma unroll
    for (int c = 0; c < 5; ++c) {
        sw[c] = w[(size_t)c * NN + n];
        mx = fmaxf(mx, sw[c]);
    }
    float sum = 0.f;
#pragma unroll
    for (int c = 0; c < 5; ++c) {
        sw[c] = expf(sw[c] - mx);
        sum += sw[c];
    }
    float inv = 1.0f / sum;
    float acc = 0.f;
#pragma unroll
    for (int c = 0; c < 5; ++c) {
        sw[c] *= inv;
        acc += sw[c] * __bfloat162float(chanEmb[((size_t)c * NN + n) * DD + lane]);
    }
    if (n < UU) {
#pragma unroll
        for (int c = 0; c < 5; ++c)
            if (lane == c) oUS[(size_t)c * UU + n] = sw[c];
        mixedRU[(size_t)n * DD + lane] = acc;
    } else {
        int m = n - UU;
#pragma unroll
        for (int c = 0; c < 5; ++c)
            if (lane == c) oIS[(size_t)c * II + m] = sw[c];
        oMI[(size_t)m * DD + lane] = acc;
    }
}

// social 2-channel softmax fuse + adaptive final combine
__global__ void social_mix_final_kernel(const float* __restrict__ e0, const float* __restrict__ e1,
                                        const float* __restrict__ vs,
                                        const float* __restrict__ mixedRU,
                                        const float* __restrict__ adaptive,
                                        float* __restrict__ scoresOut,
                                        float* __restrict__ outMU) {
    int lane = threadIdx.x & 63;
    int n = blockIdx.x * (blockDim.x >> 6) + (threadIdx.x >> 6);
    if (n >= UU) return;
    size_t idx = (size_t)n * DD + lane;
    float a = e0[idx];
    float b = e1[idx];
    float v = vs[lane];
    float pa = a * v, pb = b * v;
    float mru = mixedRU[idx];
#pragma unroll
    for (int m = 32; m >= 1; m >>= 1) { pa += __shfl_xor(pa, m, 64); pb += __shfl_xor(pb, m, 64); }
    float w0 = tanhf(pa);
    float w1 = tanhf(pb);
    float mx = fmaxf(w0, w1);
    float x0 = expf(w0 - mx);
    float x1 = expf(w1 - mx);
    float invs = 1.0f / (x0 + x1);
    float s0 = x0 * invs;
    float s1 = x1 * invs;
    if (lane == 0) {
        scoresOut[n] = s0;
        scoresOut[UU + n] = s1;
    }
    float ms = s0 * a + s1 * b;
    float nm = mru * ms, na2 = mru * mru, nb2 = ms * ms;
#pragma unroll
    for (int m = 32; m >= 1; m >>= 1) {
        nm += __shfl_xor(nm, m, 64); na2 += __shfl_xor(na2, m, 64); nb2 += __shfl_xor(nb2, m, 64);
    }
    float denom = fmaxf(sqrtf(na2), 1e-8f) * fmaxf(sqrtf(nb2), 1e-8f);
    float sim = nm / denom;
    float rate = 1.0f / (2.0f + fmaxf(sim, 0.f) * adaptive[n]);
    outMU[idx] = mru + ms * rate;
}

extern "C" void kernel_launch(void* const* d_in, const int* in_sizes, int n_in,
                              void* d_out, int out_size, void* d_ws, size_t ws_size,
                              hipStream_t stream) {
    const int* r_rows = (const int*)d_in[0];
    const int* r_cols = (const int*)d_in[1];
    const float* r_vals = (const float*)d_in[2];
    const int* f_rows = (const int*)d_in[3];
    const int* f_cols = (const int*)d_in[4];
    const float* f_vals = (const float*)d_in[5];
    const int* g_rows = (const int*)d_in[6];
    const int* g_cols = (const int*)d_in[7];
    const float* g_vals = (const float*)d_in[8];
    const float* rue = (const float*)d_in[9];
    const float* rie = (const float*)d_in[10];
    const float* femb = (const float*)d_in[11];
    const float* gemb = (const float*)d_in[12];
    const float* uaw = (const float*)d_in[13];
    const float* uamw = (const float*)d_in[14];
    const float* iaw = (const float*)d_in[15];
    const float* iamw = (const float*)d_in[16];
    const float* saw = (const float*)d_in[17];
    const float* samw = (const float*)d_in[18];
    const float* adapt = (const float*)d_in[19];

    // ws layout (float units) — total ≈ 55.4M floats ≈ 222 MB
    float* ws = (float*)d_ws;
    size_t o = 0;
    int* rowptr = (int*)(ws + o); o += 870016;        // MTOT+1
    int* bStart = (int*)(ws + o); o += 2048;          // NBCK+1
    int* bTot   = (int*)(ws + o); o += 2048;
    int* gHistT = (int*)(ws + o); o += 1800000;       // [NBCK][GRID_A]
    float* R1 = ws + o; o += 14000000;                // ecv -> AtmpB/mixedRU/socM0/socM1
    float* edF = ws + o; o += 14000000;               // edata
    float* R2 = ws + o; o += 24000000;                // chanMean -> socL1B
    float* wrat = ws + o; o += 750016;
    float* vvec = ws + o; o += 192;

    uint2* ecv = (uint2*)R1;
    uint2* edata = (uint2*)edF;
    // aliases in R1 (ecv dead after phaseB):
    uint2* AtmpB = (uint2*)R1;                        // NN*16 uint2 (4.8M floats)
    float* mixedRU = R1;                              // after rating loop (AtmpB dead at mix5)
    float* socM0 = R1 + 4800000;                      // UU*64 f32
    float* socM1 = R1 + 8640000;                      // UU*64 f32
    // aliases in R2 (chanMean dead after mix5):
    __hip_bfloat16* chanMean = (__hip_bfloat16*)R2;   // 5*NN*64 bf16
    uint2* socL1B = (uint2*)R2;                       // UU*16 uint2

    float* out = (float*)d_out;
    float* oUS = out;
    float* oIS = oUS + (size_t)5 * UU;
    float* oSS = oIS + (size_t)5 * II;
    float* oMU = oSS + (size_t)2 * UU;
    float* oMI = oMU + (size_t)UU * DD;

    const dim3 blk(256);
    const int gridN4 = (NN + 15) / 16;    // 4 rows/wave, 4 waves/block
    const int gridU4 = (UU + 15) / 16;
    const int gridMix = (NN + 3) / 4;     // wave per row
    const int gridFin = (UU + 3) / 4;

    att_vec_kernel<<<1, 64, 0, stream>>>(uaw, uamw, iaw, iamw, saw, samw, vvec);

    // ---- build row-sorted CSR for all 7 graphs ----
    pa_count_kernel<<<GRID_A, blk, 0, stream>>>(r_rows, f_rows, g_rows, gHistT);
    kprefix_kernel<<<(NBCK + 3) / 4, blk, 0, stream>>>(gHistT, bTot);
    bscan_kernel<<<1, blk, 0, stream>>>(bTot, bStart, rowptr);
    pa_scatter_kernel<<<GRID_A, blk, 0, stream>>>(r_rows, r_cols, r_vals,
                                                  f_rows, f_cols, f_vals,
                                                  g_rows, g_cols, g_vals,
                                                  bStart, gHistT, ecv);
    phaseB_kernel<<<NBCK, blk, 0, stream>>>(bStart, rowptr, ecv, edata);

    // ---- rating channels ----
    for (int c = 0; c < 5; ++c) {
        spmm_kernel<0><<<gridN4, blk, 0, stream>>>(
            rowptr, c * NN, edata,
            rue + (size_t)c * UU * DD, rie + (size_t)c * II * DD, nullptr,
            nullptr, nullptr, AtmpB, nullptr, nullptr, NN);
        spmm_kernel<1><<<gridN4, blk, 0, stream>>>(
            rowptr, c * NN, edata,
            nullptr, nullptr, AtmpB, AtmpB, vvec,
            (uint2*)(chanMean + (size_t)c * NN * DD), nullptr, wrat + (size_t)c * NN, NN);
    }

    // ---- attention fuse (rating), user+item in one launch ----
    mix5_kernel<<<gridMix, blk, 0, stream>>>(chanMean, wrat, oUS, oIS, mixedRU, oMI);

    // ---- social: friend ----
    spmm_kernel<2><<<gridU4, blk, 0, stream>>>(rowptr, ROW_S0, edata, femb, nullptr, nullptr,
                                               nullptr, nullptr, socL1B, nullptr, nullptr, UU);
    spmm_kernel<3><<<gridU4, blk, 0, stream>>>(rowptr, ROW_S0, edata, nullptr, nullptr, socL1B,
                                               socL1B, nullptr, nullptr, (float4*)socM0, nullptr, UU);
    // ---- social: group ----
    spmm_kernel<2><<<gridU4, blk, 0, stream>>>(rowptr, ROW_S0 + UU, edata, gemb, nullptr, nullptr,
                                               nullptr, nullptr, socL1B, nullptr, nullptr, UU);
    spmm_kernel<3><<<gridU4, blk, 0, stream>>>(rowptr, ROW_S0 + UU, edata, nullptr, nullptr, socL1B,
                                               socL1B, nullptr, nullptr, (float4*)socM1, nullptr, UU);

    // ---- social fuse + adaptive combine ----
    social_mix_final_kernel<<<gridFin, blk, 0, stream>>>(socM0, socM1, vvec + 2 * DD,
                                                         mixedRU, adapt, oSS, oMU);
}

// Round 8
// 668.799 us; speedup vs baseline: 4.9719x; 1.1094x over previous
//
#include <hip/hip_runtime.h>
#include <hip/hip_bf16.h>

#define UU 60000
#define II 90000
#define DD 64
#define NN 150000
#define NNZC 1000000
#define NTOT 7000000
#define MTOT 870000           // 5*NN + 2*UU
#define ROW_S0 750000         // start of social rows (5*NN)
#define NBR 733               // rating buckets (1024 rows each)
#define NBCK 1046             // + 313 social buckets (384 rows each)
#define CAPE 8192             // phaseB LDS sort capacity
#define ACH 16384             // edges per partition block (125 B bucket runs)
#define GRID_A 428            // ceil(NTOT/ACH)
#define ABLK 1024             // partition block size (16 waves -> ~84% occupancy)

__device__ __forceinline__ int wave_incl_scan(int x) {
    int lane = threadIdx.x & 63;
#pragma unroll
    for (int d = 1; d < 64; d <<= 1) {
        int y = __shfl_up(x, d, 64);
        if (lane >= d) x += y;
    }
    return x;
}

__device__ int block_incl_scan(int x, int* lds) {
    int wid = threadIdx.x >> 6, lane = threadIdx.x & 63;
    int ws_ = wave_incl_scan(x);
    if (lane == 63) lds[wid] = ws_;
    __syncthreads();
    int off = 0;
    for (int w = 0; w < wid; ++w) off += lds[w];
    __syncthreads();
    return ws_ + off;
}

__device__ __forceinline__ float2 unpack_bf16x2(unsigned p) {
    float2 r;
    r.x = __uint_as_float(p << 16);
    r.y = __uint_as_float(p & 0xffff0000u);
    return r;
}

__device__ __forceinline__ unsigned pack_bf16x2(float a, float b) {
    __hip_bfloat162 h = __float22bfloat162_rn(make_float2(a, b));
    return *(unsigned*)&h;
}

__device__ __forceinline__ uint2 pack4(float4 m) {
    return make_uint2(pack_bf16x2(m.x, m.y), pack_bf16x2(m.z, m.w));
}

__device__ __forceinline__ float4 unpack4(uint2 p) {
    float2 a = unpack_bf16x2(p.x), b = unpack_bf16x2(p.y);
    return make_float4(a.x, a.y, b.x, b.y);
}

__device__ __forceinline__ int bid_of(int grow) {
    return (grow < ROW_S0) ? (grow >> 10) : NBR + (grow - ROW_S0) / 384;
}

__device__ __forceinline__ int decode_row(int e, const int* rR, const int* fR, const int* gR) {
    if (e < 5 * NNZC) return (e / NNZC) * NN + rR[e];
    if (e < 6 * NNZC) return ROW_S0 + fR[e - 5 * NNZC];
    return ROW_S0 + UU + gR[e - 6 * NNZC];
}

__global__ void att_vec_kernel(const float* __restrict__ au, const float* __restrict__ Mu,
                               const float* __restrict__ ai, const float* __restrict__ Mi,
                               const float* __restrict__ as_, const float* __restrict__ Ms,
                               float* __restrict__ v) {
    int d = threadIdx.x;  // 64 threads
    float su = 0.f, si = 0.f, ss = 0.f;
    for (int e = 0; e < DD; ++e) {
        su += au[e] * Mu[e * DD + d];
        si += ai[e] * Mi[e * DD + d];
        ss += as_[e] * Ms[e * DD + d];
    }
    v[d] = su;
    v[DD + d] = si;
    v[2 * DD + d] = ss;
}

// per-block bucket histogram -> gHistT[bucket][block] (1.79 MB, L2-resident)
__global__ __launch_bounds__(ABLK) void pa_count_kernel(const int* __restrict__ rR,
                                                        const int* __restrict__ fR,
                                                        const int* __restrict__ gR,
                                                        int* __restrict__ gHistT) {
    __shared__ int lcnt[NBCK];
    int k = blockIdx.x;
    int cbase = k * ACH;
    int eEnd = min(cbase + ACH, NTOT);
    for (int b = threadIdx.x; b < NBCK; b += ABLK) lcnt[b] = 0;
    __syncthreads();
    for (int e = cbase + threadIdx.x; e < eEnd; e += ABLK)
        atomicAdd(&lcnt[bid_of(decode_row(e, rR, fR, gR))], 1);
    __syncthreads();
    for (int b = threadIdx.x; b < NBCK; b += ABLK)
        gHistT[(size_t)b * GRID_A + k] = lcnt[b];
}

// one wave per bucket: in-place exclusive prefix over its GRID_A block counts + total
__global__ void kprefix_kernel(int* __restrict__ gHistT, int* __restrict__ bTot) {
    int b = blockIdx.x * (blockDim.x >> 6) + (threadIdx.x >> 6);
    if (b >= NBCK) return;
    int lane = threadIdx.x & 63;
    int* g = gHistT + (size_t)b * GRID_A;
    int carry = 0;
    for (int c0 = 0; c0 < GRID_A; c0 += 64) {
        int idx = c0 + lane;
        int v = (idx < GRID_A) ? g[idx] : 0;
        int incl = wave_incl_scan(v);
        if (idx < GRID_A) g[idx] = carry + incl - v;
        carry += __shfl(incl, 63, 64);
    }
    if (lane == 0) bTot[b] = carry;
}

// single-block exclusive scan of bucket totals -> bStart; sentinels
__global__ void bscan_kernel(const int* __restrict__ bTot, int* __restrict__ bStart,
                             int* __restrict__ rowptr) {
    __shared__ int lds8[8];
    __shared__ int sOff;
    if (threadIdx.x == 0) sOff = 0;
    __syncthreads();
    for (int base = 0; base < NBCK; base += 256) {
        int i = base + threadIdx.x;
        int v = (i < NBCK) ? bTot[i] : 0;
        int incl = block_incl_scan(v, lds8);
        if (i < NBCK) bStart[i] = sOff + incl - v;
        __syncthreads();
        if (threadIdx.x == 255) sOff += incl;
        __syncthreads();
    }
    if (threadIdx.x == 0) { bStart[NBCK] = sOff; rowptr[MTOT] = sOff; }
}

// single pass: decode + write to exact compact bucket-major slot
__global__ __launch_bounds__(ABLK) void pa_scatter_kernel(
        const int* __restrict__ rR, const int* __restrict__ rC, const float* __restrict__ rV,
        const int* __restrict__ fR, const int* __restrict__ fC, const float* __restrict__ fV,
        const int* __restrict__ gR, const int* __restrict__ gC, const float* __restrict__ gV,
        const int* __restrict__ bStart, const int* __restrict__ gHistT,
        uint2* __restrict__ ecv) {
    __shared__ int lcur[NBCK];
    int k = blockIdx.x;
    int cbase = k * ACH;
    int eEnd = min(cbase + ACH, NTOT);
    for (int b = threadIdx.x; b < NBCK; b += ABLK)
        lcur[b] = bStart[b] + gHistT[(size_t)b * GRID_A + k];
    __syncthreads();
    for (int e = cbase + threadIdx.x; e < eEnd; e += ABLK) {
        int grow, c; float v;
        if (e < 5 * NNZC) { grow = (e / NNZC) * NN + rR[e]; c = rC[e]; v = rV[e]; }
        else if (e < 6 * NNZC) { int kk = e - 5 * NNZC; grow = ROW_S0 + fR[kk]; c = fC[kk]; v = fV[kk]; }
        else { int kk = e - 6 * NNZC; grow = ROW_S0 + UU + gR[kk]; c = gC[kk]; v = gV[kk]; }
        int b = bid_of(grow);
        int lrow = (grow < ROW_S0) ? (grow & 1023) : ((grow - ROW_S0) % 384);
        int pos = atomicAdd(&lcur[b], 1);
        ecv[pos] = make_uint2(((unsigned)lrow << 18) | (unsigned)c, __float_as_uint(v));
    }
}

// per-bucket LDS permutation sort -> row-sorted edata (coalesced); emits rowptr
__global__ __launch_bounds__(256) void phaseB_kernel(const int* __restrict__ bStart,
                                                     int* __restrict__ rowptr,
                                                     const uint2* __restrict__ ecv,
                                                     uint2* __restrict__ edata) {
    __shared__ unsigned short perm[CAPE];  // 16 KB
    __shared__ int off[1024];
    __shared__ int lds8[8];
    int b = blockIdx.x;
    int firstRow = (b < NBR) ? (b << 10) : ROW_S0 + (b - NBR) * 384;
    int rowEnd = (b < NBR) ? min((b + 1) << 10, ROW_S0)
                           : min(ROW_S0 + (b - NBR + 1) * 384, MTOT);
    int nRows = rowEnd - firstRow;
    int dst = bStart[b];
    int count = bStart[b + 1] - dst;
    for (int i = threadIdx.x; i < nRows; i += 256) off[i] = 0;
    __syncthreads();
    for (int i = threadIdx.x; i < count; i += 256)
        atomicAdd(&off[ecv[dst + i].x >> 18], 1);
    __syncthreads();
    int base4 = threadIdx.x * 4;
    int v4[4], s = 0;
#pragma unroll
    for (int kk = 0; kk < 4; ++kk) {
        int i = base4 + kk;
        v4[kk] = (i < nRows) ? off[i] : 0;
        s += v4[kk];
    }
    int incl = block_incl_scan(s, lds8);
    int run = incl - s;
#pragma unroll
    for (int kk = 0; kk < 4; ++kk) {
        int i = base4 + kk;
        if (i < nRows) { rowptr[firstRow + i] = dst + run; off[i] = run; }
        run += v4[kk];
    }
    __syncthreads();
    if (count <= CAPE) {
        for (int i = threadIdx.x; i < count; i += 256) {
            int pos = atomicAdd(&off[ecv[dst + i].x >> 18], 1);
            perm[pos] = (unsigned short)i;
        }
        __syncthreads();
        for (int i = threadIdx.x; i < count; i += 256) {
            uint2 e = ecv[dst + perm[i]];
            edata[dst + i] = make_uint2(e.x & 0x3FFFFu, e.y);
        }
    } else {
        for (int i = threadIdx.x; i < count; i += 256) {
            uint2 e = ecv[dst + i];
            int pos = atomicAdd(&off[e.x >> 18], 1);
            edata[dst + pos] = make_uint2(e.x & 0x3FFFFu, e.y);
        }
    }
}

// 16 lanes per row, 4 rows per wave; lane owns 4 dims end-to-end.
// Inner loop: 4 masked edges per batch -> 4 gathers in flight (MLP).
// MODE 0: gather f32 split (rue/rie)  -> out bf16 = acc          (rating L1)
// MODE 1: gather bf16 tbl; m=0.5*(acc+self); out bf16; wOut=tanh (rating L2)
// MODE 2: gather f32 (femb/gemb)      -> out bf16 = l2norm(acc)  (social L1)
// MODE 3: gather bf16 tbl -> out f32 = 0.5*(self + l2norm(acc))  (social L2)
template <int MODE>
__global__ __launch_bounds__(256) void spmm_kernel(
        const int* __restrict__ rowptr, int rowBase,
        const uint2* __restrict__ edata,
        const float* __restrict__ xloF, const float* __restrict__ xhiF,
        const uint2* __restrict__ tblB,
        const uint2* __restrict__ selfB, const float* __restrict__ vvec,
        uint2* __restrict__ outB, float4* __restrict__ outF,
        float* __restrict__ wOut, int nRows) {
    int lane = threadIdx.x & 63;
    int l16 = lane & 15;
    int grpBase = lane & 48;
    int wid = blockIdx.x * (blockDim.x >> 6) + (threadIdx.x >> 6);
    int row = wid * 4 + (lane >> 4);
    bool active = row < nRows;
    int g = rowBase + row;
    int start = active ? rowptr[g] : 0;
    int end = active ? rowptr[g + 1] : 0;
    float4 acc = make_float4(0.f, 0.f, 0.f, 0.f);
    for (int j0 = start; j0 < end; j0 += 16) {
        uint2 md = make_uint2(0u, 0u);
        if (j0 + l16 < end) md = edata[j0 + l16];
        int cnt = min(end - j0, 16);
        for (int js = 0; js < cnt; js += 4) {
            int cc[4]; float vv[4]; float4 xv[4];
#pragma unroll
            for (int u = 0; u < 4; ++u) {
                int jj = js + u;
                int sl = grpBase + ((jj < cnt) ? jj : 0);
                cc[u] = __shfl((int)md.x, sl, 64);
                float v = __uint_as_float((unsigned)__shfl((int)md.y, sl, 64));
                vv[u] = (jj < cnt) ? v : 0.f;
            }
#pragma unroll
            for (int u = 0; u < 4; ++u) {
                int c = cc[u];
                if (MODE == 0) {
                    const float* src = (c < UU) ? (xloF + (size_t)c * DD)
                                                : (xhiF + (size_t)(c - UU) * DD);
                    xv[u] = *(const float4*)(src + 4 * l16);
                } else if (MODE == 2) {
                    xv[u] = *(const float4*)(xloF + (size_t)c * DD + 4 * l16);
                } else {
                    xv[u] = unpack4(tblB[(size_t)c * 16 + l16]);
                }
            }
#pragma unroll
            for (int u = 0; u < 4; ++u) {
                acc.x += vv[u] * xv[u].x; acc.y += vv[u] * xv[u].y;
                acc.z += vv[u] * xv[u].z; acc.w += vv[u] * xv[u].w;
            }
        }
    }
    if (!active) return;
    size_t ro = (size_t)row * 16 + l16;
    if (MODE == 0) {
        outB[ro] = pack4(acc);
    } else if (MODE == 1) {
        float4 sv = unpack4(selfB[ro]);
        float4 m = make_float4(0.5f * (acc.x + sv.x), 0.5f * (acc.y + sv.y),
                               0.5f * (acc.z + sv.z), 0.5f * (acc.w + sv.w));
        outB[ro] = pack4(m);
        const float* vv = (row < UU) ? vvec : (vvec + DD);
        float4 vw = *(const float4*)(vv + 4 * l16);
        float p = m.x * vw.x + m.y * vw.y + m.z * vw.z + m.w * vw.w;
        p += __shfl_xor(p, 1, 64); p += __shfl_xor(p, 2, 64);
        p += __shfl_xor(p, 4, 64); p += __shfl_xor(p, 8, 64);
        if (l16 == 0) wOut[row] = tanhf(p);
    } else if (MODE == 2) {
        float n2 = acc.x * acc.x + acc.y * acc.y + acc.z * acc.z + acc.w * acc.w;
        n2 += __shfl_xor(n2, 1, 64); n2 += __shfl_xor(n2, 2, 64);
        n2 += __shfl_xor(n2, 4, 64); n2 += __shfl_xor(n2, 8, 64);
        float inv = 1.f / fmaxf(sqrtf(n2), 1e-12f);
        outB[ro] = pack4(make_float4(acc.x * inv, acc.y * inv, acc.z * inv, acc.w * inv));
    } else {
        float n2 = acc.x * acc.x + acc.y * acc.y + acc.z * acc.z + acc.w * acc.w;
        n2 += __shfl_xor(n2, 1, 64); n2 += __shfl_xor(n2, 2, 64);
        n2 += __shfl_xor(n2, 4, 64); n2 += __shfl_xor(n2, 8, 64);
        float inv = 1.f / fmaxf(sqrtf(n2), 1e-12f);
        float4 sv = unpack4(selfB[ro]);
        outF[ro] = make_float4(0.5f * (sv.x + acc.x * inv), 0.5f * (sv.y + acc.y * inv),
                               0.5f * (sv.z + acc.z * inv), 0.5f * (sv.w + acc.w * inv));
    }
}

// fused user+item 5-channel softmax mix (wave per row, grid over NN)
__global__ void mix5_kernel(const __hip_bfloat16* __restrict__ chanEmb,
                            const float* __restrict__ w,
                            float* __restrict__ oUS, float* __restrict__ oIS,
                            float* __restrict__ mixedRU, float* __restrict__ oMI) {
    int lane = threadIdx.x & 63;
    int n = blockIdx.x * (blockDim.x >> 6) + (threadIdx.x >> 6);
    if (n >= NN) return;
    float sw[5];
    float mx = -2.0f;
#pragma unroll
    for (int c = 0; c < 5; ++c) {
        sw[c] = w[(size_t)c * NN + n];
        mx = fmaxf(mx, sw[c]);
    }
    float sum = 0.f;
#pragma unroll
    for (int c = 0; c < 5; ++c) {
        sw[c] = expf(sw[c] - mx);
        sum += sw[c];
    }
    float inv = 1.0f / sum;
    float acc = 0.f;
#pragma unroll
    for (int c = 0; c < 5; ++c) {
        sw[c] *= inv;
        acc += sw[c] * __bfloat162float(chanEmb[((size_t)c * NN + n) * DD + lane]);
    }
    if (n < UU) {
#pragma unroll
        for (int c = 0; c < 5; ++c)
            if (lane == c) oUS[(size_t)c * UU + n] = sw[c];
        mixedRU[(size_t)n * DD + lane] = acc;
    } else {
        int m = n - UU;
#pragma unroll
        for (int c = 0; c < 5; ++c)
            if (lane == c) oIS[(size_t)c * II + m] = sw[c];
        oMI[(size_t)m * DD + lane] = acc;
    }
}

// social 2-channel softmax fuse + adaptive final combine
__global__ void social_mix_final_kernel(const float* __restrict__ e0, const float* __restrict__ e1,
                                        const float* __restrict__ vs,
                                        const float* __restrict__ mixedRU,
                                        const float* __restrict__ adaptive,
                                        float* __restrict__ scoresOut,
                                        float* __restrict__ outMU) {
    int lane = threadIdx.x & 63;
    int n = blockIdx.x * (blockDim.x >> 6) + (threadIdx.x >> 6);
    if (n >= UU) return;
    size_t idx = (size_t)n * DD + lane;
    float a = e0[idx];
    float b = e1[idx];
    float v = vs[lane];
    float pa = a * v, pb = b * v;
    float mru = mixedRU[idx];
#pragma unroll
    for (int m = 32; m >= 1; m >>= 1) { pa += __shfl_xor(pa, m, 64); pb += __shfl_xor(pb, m, 64); }
    float w0 = tanhf(pa);
    float w1 = tanhf(pb);
    float mx = fmaxf(w0, w1);
    float x0 = expf(w0 - mx);
    float x1 = expf(w1 - mx);
    float invs = 1.0f / (x0 + x1);
    float s0 = x0 * invs;
    float s1 = x1 * invs;
    if (lane == 0) {
        scoresOut[n] = s0;
        scoresOut[UU + n] = s1;
    }
    float ms = s0 * a + s1 * b;
    float nm = mru * ms, na2 = mru * mru, nb2 = ms * ms;
#pragma unroll
    for (int m = 32; m >= 1; m >>= 1) {
        nm += __shfl_xor(nm, m, 64); na2 += __shfl_xor(na2, m, 64); nb2 += __shfl_xor(nb2, m, 64);
    }
    float denom = fmaxf(sqrtf(na2), 1e-8f) * fmaxf(sqrtf(nb2), 1e-8f);
    float sim = nm / denom;
    float rate = 1.0f / (2.0f + fmaxf(sim, 0.f) * adaptive[n]);
    outMU[idx] = mru + ms * rate;
}

extern "C" void kernel_launch(void* const* d_in, const int* in_sizes, int n_in,
                              void* d_out, int out_size, void* d_ws, size_t ws_size,
                              hipStream_t stream) {
    const int* r_rows = (const int*)d_in[0];
    const int* r_cols = (const int*)d_in[1];
    const float* r_vals = (const float*)d_in[2];
    const int* f_rows = (const int*)d_in[3];
    const int* f_cols = (const int*)d_in[4];
    const float* f_vals = (const float*)d_in[5];
    const int* g_rows = (const int*)d_in[6];
    const int* g_cols = (const int*)d_in[7];
    const float* g_vals = (const float*)d_in[8];
    const float* rue = (const float*)d_in[9];
    const float* rie = (const float*)d_in[10];
    const float* femb = (const float*)d_in[11];
    const float* gemb = (const float*)d_in[12];
    const float* uaw = (const float*)d_in[13];
    const float* uamw = (const float*)d_in[14];
    const float* iaw = (const float*)d_in[15];
    const float* iamw = (const float*)d_in[16];
    const float* saw = (const float*)d_in[17];
    const float* samw = (const float*)d_in[18];
    const float* adapt = (const float*)d_in[19];

    // ws layout (float units) — total ≈ 54.1M floats ≈ 216 MB
    float* ws = (float*)d_ws;
    size_t o = 0;
    int* rowptr = (int*)(ws + o); o += 870016;        // MTOT+1
    int* bStart = (int*)(ws + o); o += 2048;          // NBCK+1
    int* bTot   = (int*)(ws + o); o += 2048;
    int* gHistT = (int*)(ws + o); o += 448000;        // [NBCK][GRID_A]
    float* R1 = ws + o; o += 14000000;                // ecv -> AtmpB/mixedRU/socM0/socM1
    float* edF = ws + o; o += 14000000;               // edata
    float* R2 = ws + o; o += 24000000;                // chanMean -> socL1B
    float* wrat = ws + o; o += 750016;
    float* vvec = ws + o; o += 192;

    uint2* ecv = (uint2*)R1;
    uint2* edata = (uint2*)edF;
    // aliases in R1 (ecv dead after phaseB):
    uint2* AtmpB = (uint2*)R1;                        // NN*16 uint2 (4.8M floats)
    float* mixedRU = R1;                              // after rating loop (AtmpB dead at mix5)
    float* socM0 = R1 + 4800000;                      // UU*64 f32
    float* socM1 = R1 + 8640000;                      // UU*64 f32
    // aliases in R2 (chanMean dead after mix5):
    __hip_bfloat16* chanMean = (__hip_bfloat16*)R2;   // 5*NN*64 bf16
    uint2* socL1B = (uint2*)R2;                       // UU*16 uint2

    float* out = (float*)d_out;
    float* oUS = out;
    float* oIS = oUS + (size_t)5 * UU;
    float* oSS = oIS + (size_t)5 * II;
    float* oMU = oSS + (size_t)2 * UU;
    float* oMI = oMU + (size_t)UU * DD;

    const dim3 blk(256);
    const dim3 blkA(ABLK);
    const int gridN4 = (NN + 15) / 16;    // 4 rows/wave, 4 waves/block
    const int gridU4 = (UU + 15) / 16;
    const int gridMix = (NN + 3) / 4;     // wave per row
    const int gridFin = (UU + 3) / 4;

    att_vec_kernel<<<1, 64, 0, stream>>>(uaw, uamw, iaw, iamw, saw, samw, vvec);

    // ---- build row-sorted CSR for all 7 graphs ----
    pa_count_kernel<<<GRID_A, blkA, 0, stream>>>(r_rows, f_rows, g_rows, gHistT);
    kprefix_kernel<<<(NBCK + 3) / 4, blk, 0, stream>>>(gHistT, bTot);
    bscan_kernel<<<1, blk, 0, stream>>>(bTot, bStart, rowptr);
    pa_scatter_kernel<<<GRID_A, blkA, 0, stream>>>(r_rows, r_cols, r_vals,
                                                   f_rows, f_cols, f_vals,
                                                   g_rows, g_cols, g_vals,
                                                   bStart, gHistT, ecv);
    phaseB_kernel<<<NBCK, blk, 0, stream>>>(bStart, rowptr, ecv, edata);

    // ---- rating channels ----
    for (int c = 0; c < 5; ++c) {
        spmm_kernel<0><<<gridN4, blk, 0, stream>>>(
            rowptr, c * NN, edata,
            rue + (size_t)c * UU * DD, rie + (size_t)c * II * DD, nullptr,
            nullptr, nullptr, AtmpB, nullptr, nullptr, NN);
        spmm_kernel<1><<<gridN4, blk, 0, stream>>>(
            rowptr, c * NN, edata,
            nullptr, nullptr, AtmpB, AtmpB, vvec,
            (uint2*)(chanMean + (size_t)c * NN * DD), nullptr, wrat + (size_t)c * NN, NN);
    }

    // ---- attention fuse (rating), user+item in one launch ----
    mix5_kernel<<<gridMix, blk, 0, stream>>>(chanMean, wrat, oUS, oIS, mixedRU, oMI);

    // ---- social: friend ----
    spmm_kernel<2><<<gridU4, blk, 0, stream>>>(rowptr, ROW_S0, edata, femb, nullptr, nullptr,
                                               nullptr, nullptr, socL1B, nullptr, nullptr, UU);
    spmm_kernel<3><<<gridU4, blk, 0, stream>>>(rowptr, ROW_S0, edata, nullptr, nullptr, socL1B,
                                               socL1B, nullptr, nullptr, (float4*)socM0, nullptr, UU);
    // ---- social: group ----
    spmm_kernel<2><<<gridU4, blk, 0, stream>>>(rowptr, ROW_S0 + UU, edata, gemb, nullptr, nullptr,
                                               nullptr, nullptr, socL1B, nullptr, nullptr, UU);
    spmm_kernel<3><<<gridU4, blk, 0, stream>>>(rowptr, ROW_S0 + UU, edata, nullptr, nullptr, socL1B,
                                               socL1B, nullptr, nullptr, (float4*)socM1, nullptr, UU);

    // ---- social fuse + adaptive combine ----
    social_mix_final_kernel<<<gridFin, blk, 0, stream>>>(socM0, socM1, vvec + 2 * DD,
                                                         mixedRU, adapt, oSS, oMU);
}

// Round 9
// 662.610 us; speedup vs baseline: 5.0184x; 1.0093x over previous
//
#include <hip/hip_runtime.h>
#include <hip/hip_bf16.h>

#define UU 60000
#define II 90000
#define DD 64
#define NN 150000
#define NNZC 1000000
#define NTOT 7000000
#define MTOT 870000           // 5*NN + 2*UU
#define ROW_S0 750000         // start of social rows (5*NN)
#define NBR 733               // rating buckets (1024 rows each)
#define NBCK 1046             // + 313 social buckets (384 rows each)
#define CAPE 8192             // phaseB LDS sort capacity
#define ACH 16384             // edges per partition block (125 B bucket runs)
#define GRID_A 428            // ceil(NTOT/ACH)
#define ABLK 1024             // partition block size

__device__ __forceinline__ int wave_incl_scan(int x) {
    int lane = threadIdx.x & 63;
#pragma unroll
    for (int d = 1; d < 64; d <<= 1) {
        int y = __shfl_up(x, d, 64);
        if (lane >= d) x += y;
    }
    return x;
}

__device__ int block_incl_scan(int x, int* lds) {
    int wid = threadIdx.x >> 6, lane = threadIdx.x & 63;
    int ws_ = wave_incl_scan(x);
    if (lane == 63) lds[wid] = ws_;
    __syncthreads();
    int off = 0;
    for (int w = 0; w < wid; ++w) off += lds[w];
    __syncthreads();
    return ws_ + off;
}

__device__ __forceinline__ float2 unpack_bf16x2(unsigned p) {
    float2 r;
    r.x = __uint_as_float(p << 16);
    r.y = __uint_as_float(p & 0xffff0000u);
    return r;
}

__device__ __forceinline__ unsigned pack_bf16x2(float a, float b) {
    __hip_bfloat162 h = __float22bfloat162_rn(make_float2(a, b));
    return *(unsigned*)&h;
}

__device__ __forceinline__ uint2 pack4(float4 m) {
    return make_uint2(pack_bf16x2(m.x, m.y), pack_bf16x2(m.z, m.w));
}

__device__ __forceinline__ float4 unpack4(uint2 p) {
    float2 a = unpack_bf16x2(p.x), b = unpack_bf16x2(p.y);
    return make_float4(a.x, a.y, b.x, b.y);
}

__device__ __forceinline__ int bid_of(int grow) {
    return (grow < ROW_S0) ? (grow >> 10) : NBR + (grow - ROW_S0) / 384;
}

__global__ void att_vec_kernel(const float* __restrict__ au, const float* __restrict__ Mu,
                               const float* __restrict__ ai, const float* __restrict__ Mi,
                               const float* __restrict__ as_, const float* __restrict__ Ms,
                               float* __restrict__ v) {
    int d = threadIdx.x;  // 64 threads
    float su = 0.f, si = 0.f, ss = 0.f;
    for (int e = 0; e < DD; ++e) {
        su += au[e] * Mu[e * DD + d];
        si += ai[e] * Mi[e * DD + d];
        ss += as_[e] * Ms[e * DD + d];
    }
    v[d] = su;
    v[DD + d] = si;
    v[2 * DD + d] = ss;
}

// batched decode of edge e -> global row (+ optionally col/val)
__device__ __forceinline__ void decode_full(int e, const int* __restrict__ rR,
                                            const int* __restrict__ rC, const float* __restrict__ rV,
                                            const int* __restrict__ fR, const int* __restrict__ fC,
                                            const float* __restrict__ fV,
                                            const int* __restrict__ gR, const int* __restrict__ gC,
                                            const float* __restrict__ gV,
                                            int& grow, int& c, float& v) {
    if (e < 5 * NNZC) { grow = (e / NNZC) * NN + rR[e]; c = rC[e]; v = rV[e]; }
    else if (e < 6 * NNZC) { int k = e - 5 * NNZC; grow = ROW_S0 + fR[k]; c = fC[k]; v = fV[k]; }
    else { int k = e - 6 * NNZC; grow = ROW_S0 + UU + gR[k]; c = gC[k]; v = gV[k]; }
}

// per-block bucket histogram -> gHistT[bucket][block]; 4-edge MLP batches
__global__ __launch_bounds__(ABLK) void pa_count_kernel(const int* __restrict__ rR,
                                                        const int* __restrict__ fR,
                                                        const int* __restrict__ gR,
                                                        int* __restrict__ gHistT) {
    __shared__ int lcnt[NBCK];
    int k = blockIdx.x;
    int cbase = k * ACH;
    int eEnd = min(cbase + ACH, NTOT);
    for (int b = threadIdx.x; b < NBCK; b += ABLK) lcnt[b] = 0;
    __syncthreads();
    for (int e0 = cbase + threadIdx.x; e0 < eEnd; e0 += 4 * ABLK) {
        int gw[4]; bool val[4];
#pragma unroll
        for (int u = 0; u < 4; ++u) {
            int e = e0 + u * ABLK;
            val[u] = e < eEnd;
            int ec = val[u] ? e : cbase;
            if (ec < 5 * NNZC) gw[u] = (ec / NNZC) * NN + rR[ec];
            else if (ec < 6 * NNZC) gw[u] = ROW_S0 + fR[ec - 5 * NNZC];
            else gw[u] = ROW_S0 + UU + gR[ec - 6 * NNZC];
        }
#pragma unroll
        for (int u = 0; u < 4; ++u)
            if (val[u]) atomicAdd(&lcnt[bid_of(gw[u])], 1);
    }
    __syncthreads();
    for (int b = threadIdx.x; b < NBCK; b += ABLK)
        gHistT[(size_t)b * GRID_A + k] = lcnt[b];
}

// one wave per bucket: in-place exclusive prefix over its GRID_A block counts + total
__global__ void kprefix_kernel(int* __restrict__ gHistT, int* __restrict__ bTot) {
    int b = blockIdx.x * (blockDim.x >> 6) + (threadIdx.x >> 6);
    if (b >= NBCK) return;
    int lane = threadIdx.x & 63;
    int* g = gHistT + (size_t)b * GRID_A;
    int carry = 0;
    for (int c0 = 0; c0 < GRID_A; c0 += 64) {
        int idx = c0 + lane;
        int v = (idx < GRID_A) ? g[idx] : 0;
        int incl = wave_incl_scan(v);
        if (idx < GRID_A) g[idx] = carry + incl - v;
        carry += __shfl(incl, 63, 64);
    }
    if (lane == 0) bTot[b] = carry;
}

// single-block exclusive scan of bucket totals -> bStart; sentinels
__global__ void bscan_kernel(const int* __restrict__ bTot, int* __restrict__ bStart,
                             int* __restrict__ rowptr) {
    __shared__ int lds8[8];
    __shared__ int sOff;
    if (threadIdx.x == 0) sOff = 0;
    __syncthreads();
    for (int base = 0; base < NBCK; base += 256) {
        int i = base + threadIdx.x;
        int v = (i < NBCK) ? bTot[i] : 0;
        int incl = block_incl_scan(v, lds8);
        if (i < NBCK) bStart[i] = sOff + incl - v;
        __syncthreads();
        if (threadIdx.x == 255) sOff += incl;
        __syncthreads();
    }
    if (threadIdx.x == 0) { bStart[NBCK] = sOff; rowptr[MTOT] = sOff; }
}

// single pass: decode + write to exact compact bucket-major slot; 4-edge MLP batches
__global__ __launch_bounds__(ABLK) void pa_scatter_kernel(
        const int* __restrict__ rR, const int* __restrict__ rC, const float* __restrict__ rV,
        const int* __restrict__ fR, const int* __restrict__ fC, const float* __restrict__ fV,
        const int* __restrict__ gR, const int* __restrict__ gC, const float* __restrict__ gV,
        const int* __restrict__ bStart, const int* __restrict__ gHistT,
        uint2* __restrict__ ecv) {
    __shared__ int lcur[NBCK];
    int k = blockIdx.x;
    int cbase = k * ACH;
    int eEnd = min(cbase + ACH, NTOT);
    for (int b = threadIdx.x; b < NBCK; b += ABLK)
        lcur[b] = bStart[b] + gHistT[(size_t)b * GRID_A + k];
    __syncthreads();
    for (int e0 = cbase + threadIdx.x; e0 < eEnd; e0 += 4 * ABLK) {
        int gw[4], cc[4]; float vv[4]; bool val[4];
#pragma unroll
        for (int u = 0; u < 4; ++u) {
            int e = e0 + u * ABLK;
            val[u] = e < eEnd;
            int ec = val[u] ? e : cbase;
            decode_full(ec, rR, rC, rV, fR, fC, fV, gR, gC, gV, gw[u], cc[u], vv[u]);
        }
        int pos[4];
#pragma unroll
        for (int u = 0; u < 4; ++u)
            pos[u] = val[u] ? atomicAdd(&lcur[bid_of(gw[u])], 1) : 0;
#pragma unroll
        for (int u = 0; u < 4; ++u) {
            if (!val[u]) continue;
            int lrow = (gw[u] < ROW_S0) ? (gw[u] & 1023) : ((gw[u] - ROW_S0) % 384);
            ecv[pos[u]] = make_uint2(((unsigned)lrow << 18) | (unsigned)cc[u],
                                     __float_as_uint(vv[u]));
        }
    }
}

// per-bucket LDS permutation sort -> row-sorted edata (coalesced); emits rowptr
__global__ __launch_bounds__(256) void phaseB_kernel(const int* __restrict__ bStart,
                                                     int* __restrict__ rowptr,
                                                     const uint2* __restrict__ ecv,
                                                     uint2* __restrict__ edata) {
    __shared__ unsigned short perm[CAPE];  // 16 KB
    __shared__ int off[1024];
    __shared__ int lds8[8];
    int b = blockIdx.x;
    int firstRow = (b < NBR) ? (b << 10) : ROW_S0 + (b - NBR) * 384;
    int rowEnd = (b < NBR) ? min((b + 1) << 10, ROW_S0)
                           : min(ROW_S0 + (b - NBR + 1) * 384, MTOT);
    int nRows = rowEnd - firstRow;
    int dst = bStart[b];
    int count = bStart[b + 1] - dst;
    for (int i = threadIdx.x; i < nRows; i += 256) off[i] = 0;
    __syncthreads();
    for (int i = threadIdx.x; i < count; i += 256)
        atomicAdd(&off[ecv[dst + i].x >> 18], 1);
    __syncthreads();
    int base4 = threadIdx.x * 4;
    int v4[4], s = 0;
#pragma unroll
    for (int kk = 0; kk < 4; ++kk) {
        int i = base4 + kk;
        v4[kk] = (i < nRows) ? off[i] : 0;
        s += v4[kk];
    }
    int incl = block_incl_scan(s, lds8);
    int run = incl - s;
#pragma unroll
    for (int kk = 0; kk < 4; ++kk) {
        int i = base4 + kk;
        if (i < nRows) { rowptr[firstRow + i] = dst + run; off[i] = run; }
        run += v4[kk];
    }
    __syncthreads();
    if (count <= CAPE) {
        for (int i = threadIdx.x; i < count; i += 256) {
            int pos = atomicAdd(&off[ecv[dst + i].x >> 18], 1);
            perm[pos] = (unsigned short)i;
        }
        __syncthreads();
        for (int i = threadIdx.x; i < count; i += 256) {
            uint2 e = ecv[dst + perm[i]];
            edata[dst + i] = make_uint2(e.x & 0x3FFFFu, e.y);
        }
    } else {
        for (int i = threadIdx.x; i < count; i += 256) {
            uint2 e = ecv[dst + i];
            int pos = atomicAdd(&off[e.x >> 18], 1);
            edata[dst + pos] = make_uint2(e.x & 0x3FFFFu, e.y);
        }
    }
}

// 16 lanes per row, 4 rows per wave; lane owns 4 dims end-to-end.
// Inner loop: 8 masked edges per batch -> 8 gathers in flight (covers avg deg 6.7 in 1 round).
// MODE 0: gather f32 split (rue/rie)  -> out bf16 = acc          (rating L1)
// MODE 1: gather bf16 tbl; m=0.5*(acc+self); out bf16; wOut=tanh (rating L2)
// MODE 2: gather f32 (femb/gemb)      -> out bf16 = l2norm(acc)  (social L1)
// MODE 3: gather bf16 tbl -> out f32 = 0.5*(self + l2norm(acc))  (social L2)
template <int MODE>
__global__ __launch_bounds__(256) void spmm_kernel(
        const int* __restrict__ rowptr, int rowBase,
        const uint2* __restrict__ edata,
        const float* __restrict__ xloF, const float* __restrict__ xhiF,
        const uint2* __restrict__ tblB,
        const uint2* __restrict__ selfB, const float* __restrict__ vvec,
        uint2* __restrict__ outB, float4* __restrict__ outF,
        float* __restrict__ wOut, int nRows) {
    int lane = threadIdx.x & 63;
    int l16 = lane & 15;
    int grpBase = lane & 48;
    int wid = blockIdx.x * (blockDim.x >> 6) + (threadIdx.x >> 6);
    int row = wid * 4 + (lane >> 4);
    bool active = row < nRows;
    int g = rowBase + row;
    int start = active ? rowptr[g] : 0;
    int end = active ? rowptr[g + 1] : 0;
    float4 acc = make_float4(0.f, 0.f, 0.f, 0.f);
    for (int j0 = start; j0 < end; j0 += 16) {
        uint2 md = make_uint2(0u, 0u);
        if (j0 + l16 < end) md = edata[j0 + l16];
        int cnt = min(end - j0, 16);
        for (int js = 0; js < cnt; js += 8) {
            int cc[8]; float vv[8]; float4 xv[8];
#pragma unroll
            for (int u = 0; u < 8; ++u) {
                int jj = js + u;
                int sl = grpBase + ((jj < cnt) ? jj : 0);
                cc[u] = __shfl((int)md.x, sl, 64);
                float v = __uint_as_float((unsigned)__shfl((int)md.y, sl, 64));
                vv[u] = (jj < cnt) ? v : 0.f;
            }
#pragma unroll
            for (int u = 0; u < 8; ++u) {
                int c = cc[u];
                if (MODE == 0) {
                    const float* src = (c < UU) ? (xloF + (size_t)c * DD)
                                                : (xhiF + (size_t)(c - UU) * DD);
                    xv[u] = *(const float4*)(src + 4 * l16);
                } else if (MODE == 2) {
                    xv[u] = *(const float4*)(xloF + (size_t)c * DD + 4 * l16);
                } else {
                    xv[u] = unpack4(tblB[(size_t)c * 16 + l16]);
                }
            }
#pragma unroll
            for (int u = 0; u < 8; ++u) {
                acc.x += vv[u] * xv[u].x; acc.y += vv[u] * xv[u].y;
                acc.z += vv[u] * xv[u].z; acc.w += vv[u] * xv[u].w;
            }
        }
    }
    if (!active) return;
    size_t ro = (size_t)row * 16 + l16;
    if (MODE == 0) {
        outB[ro] = pack4(acc);
    } else if (MODE == 1) {
        float4 sv = unpack4(selfB[ro]);
        float4 m = make_float4(0.5f * (acc.x + sv.x), 0.5f * (acc.y + sv.y),
                               0.5f * (acc.z + sv.z), 0.5f * (acc.w + sv.w));
        outB[ro] = pack4(m);
        const float* vv = (row < UU) ? vvec : (vvec + DD);
        float4 vw = *(const float4*)(vv + 4 * l16);
        float p = m.x * vw.x + m.y * vw.y + m.z * vw.z + m.w * vw.w;
        p += __shfl_xor(p, 1, 64); p += __shfl_xor(p, 2, 64);
        p += __shfl_xor(p, 4, 64); p += __shfl_xor(p, 8, 64);
        if (l16 == 0) wOut[row] = tanhf(p);
    } else if (MODE == 2) {
        float n2 = acc.x * acc.x + acc.y * acc.y + acc.z * acc.z + acc.w * acc.w;
        n2 += __shfl_xor(n2, 1, 64); n2 += __shfl_xor(n2, 2, 64);
        n2 += __shfl_xor(n2, 4, 64); n2 += __shfl_xor(n2, 8, 64);
        float inv = 1.f / fmaxf(sqrtf(n2), 1e-12f);
        outB[ro] = pack4(make_float4(acc.x * inv, acc.y * inv, acc.z * inv, acc.w * inv));
    } else {
        float n2 = acc.x * acc.x + acc.y * acc.y + acc.z * acc.z + acc.w * acc.w;
        n2 += __shfl_xor(n2, 1, 64); n2 += __shfl_xor(n2, 2, 64);
        n2 += __shfl_xor(n2, 4, 64); n2 += __shfl_xor(n2, 8, 64);
        float inv = 1.f / fmaxf(sqrtf(n2), 1e-12f);
        float4 sv = unpack4(selfB[ro]);
        outF[ro] = make_float4(0.5f * (sv.x + acc.x * inv), 0.5f * (sv.y + acc.y * inv),
                               0.5f * (sv.z + acc.z * inv), 0.5f * (sv.w + acc.w * inv));
    }
}

// fused user+item 5-channel softmax mix (wave per row, grid over NN)
__global__ void mix5_kernel(const __hip_bfloat16* __restrict__ chanEmb,
                            const float* __restrict__ w,
                            float* __restrict__ oUS, float* __restrict__ oIS,
                            float* __restrict__ mixedRU, float* __restrict__ oMI) {
    int lane = threadIdx.x & 63;
    int n = blockIdx.x * (blockDim.x >> 6) + (threadIdx.x >> 6);
    if (n >= NN) return;
    float sw[5];
    float mx = -2.0f;
#pragma unroll
    for (int c = 0; c < 5; ++c) {
        sw[c] = w[(size_t)c * NN + n];
        mx = fmaxf(mx, sw[c]);
    }
    float sum = 0.f;
#pragma unroll
    for (int c = 0; c < 5; ++c) {
        sw[c] = expf(sw[c] - mx);
        sum += sw[c];
    }
    float inv = 1.0f / sum;
    float acc = 0.f;
#pragma unroll
    for (int c = 0; c < 5; ++c) {
        sw[c] *= inv;
        acc += sw[c] * __bfloat162float(chanEmb[((size_t)c * NN + n) * DD + lane]);
    }
    if (n < UU) {
#pragma unroll
        for (int c = 0; c < 5; ++c)
            if (lane == c) oUS[(size_t)c * UU + n] = sw[c];
        mixedRU[(size_t)n * DD + lane] = acc;
    } else {
        int m = n - UU;
#pragma unroll
        for (int c = 0; c < 5; ++c)
            if (lane == c) oIS[(size_t)c * II + m] = sw[c];
        oMI[(size_t)m * DD + lane] = acc;
    }
}

// social 2-channel softmax fuse + adaptive final combine
__global__ void social_mix_final_kernel(const float* __restrict__ e0, const float* __restrict__ e1,
                                        const float* __restrict__ vs,
                                        const float* __restrict__ mixedRU,
                                        const float* __restrict__ adaptive,
                                        float* __restrict__ scoresOut,
                                        float* __restrict__ outMU) {
    int lane = threadIdx.x & 63;
    int n = blockIdx.x * (blockDim.x >> 6) + (threadIdx.x >> 6);
    if (n >= UU) return;
    size_t idx = (size_t)n * DD + lane;
    float a = e0[idx];
    float b = e1[idx];
    float v = vs[lane];
    float pa = a * v, pb = b * v;
    float mru = mixedRU[idx];
#pragma unroll
    for (int m = 32; m >= 1; m >>= 1) { pa += __shfl_xor(pa, m, 64); pb += __shfl_xor(pb, m, 64); }
    float w0 = tanhf(pa);
    float w1 = tanhf(pb);
    float mx = fmaxf(w0, w1);
    float x0 = expf(w0 - mx);
    float x1 = expf(w1 - mx);
    float invs = 1.0f / (x0 + x1);
    float s0 = x0 * invs;
    float s1 = x1 * invs;
    if (lane == 0) {
        scoresOut[n] = s0;
        scoresOut[UU + n] = s1;
    }
    float ms = s0 * a + s1 * b;
    float nm = mru * ms, na2 = mru * mru, nb2 = ms * ms;
#pragma unroll
    for (int m = 32; m >= 1; m >>= 1) {
        nm += __shfl_xor(nm, m, 64); na2 += __shfl_xor(na2, m, 64); nb2 += __shfl_xor(nb2, m, 64);
    }
    float denom = fmaxf(sqrtf(na2), 1e-8f) * fmaxf(sqrtf(nb2), 1e-8f);
    float sim = nm / denom;
    float rate = 1.0f / (2.0f + fmaxf(sim, 0.f) * adaptive[n]);
    outMU[idx] = mru + ms * rate;
}

extern "C" void kernel_launch(void* const* d_in, const int* in_sizes, int n_in,
                              void* d_out, int out_size, void* d_ws, size_t ws_size,
                              hipStream_t stream) {
    const int* r_rows = (const int*)d_in[0];
    const int* r_cols = (const int*)d_in[1];
    const float* r_vals = (const float*)d_in[2];
    const int* f_rows = (const int*)d_in[3];
    const int* f_cols = (const int*)d_in[4];
    const float* f_vals = (const float*)d_in[5];
    const int* g_rows = (const int*)d_in[6];
    const int* g_cols = (const int*)d_in[7];
    const float* g_vals = (const float*)d_in[8];
    const float* rue = (const float*)d_in[9];
    const float* rie = (const float*)d_in[10];
    const float* femb = (const float*)d_in[11];
    const float* gemb = (const float*)d_in[12];
    const float* uaw = (const float*)d_in[13];
    const float* uamw = (const float*)d_in[14];
    const float* iaw = (const float*)d_in[15];
    const float* iamw = (const float*)d_in[16];
    const float* saw = (const float*)d_in[17];
    const float* samw = (const float*)d_in[18];
    const float* adapt = (const float*)d_in[19];

    // ws layout (float units) — total ≈ 54.1M floats ≈ 216 MB
    float* ws = (float*)d_ws;
    size_t o = 0;
    int* rowptr = (int*)(ws + o); o += 870016;        // MTOT+1
    int* bStart = (int*)(ws + o); o += 2048;          // NBCK+1
    int* bTot   = (int*)(ws + o); o += 2048;
    int* gHistT = (int*)(ws + o); o += 448000;        // [NBCK][GRID_A]
    float* R1 = ws + o; o += 14000000;                // ecv -> AtmpB/mixedRU/socM0/socM1
    float* edF = ws + o; o += 14000000;               // edata
    float* R2 = ws + o; o += 24000000;                // chanMean -> socL1B
    float* wrat = ws + o; o += 750016;
    float* vvec = ws + o; o += 192;

    uint2* ecv = (uint2*)R1;
    uint2* edata = (uint2*)edF;
    // aliases in R1 (ecv dead after phaseB):
    uint2* AtmpB = (uint2*)R1;                        // NN*16 uint2 (4.8M floats)
    float* mixedRU = R1;                              // after rating loop (AtmpB dead at mix5)
    float* socM0 = R1 + 4800000;                      // UU*64 f32
    float* socM1 = R1 + 8640000;                      // UU*64 f32
    // aliases in R2 (chanMean dead after mix5):
    __hip_bfloat16* chanMean = (__hip_bfloat16*)R2;   // 5*NN*64 bf16
    uint2* socL1B = (uint2*)R2;                       // UU*16 uint2

    float* out = (float*)d_out;
    float* oUS = out;
    float* oIS = oUS + (size_t)5 * UU;
    float* oSS = oIS + (size_t)5 * II;
    float* oMU = oSS + (size_t)2 * UU;
    float* oMI = oMU + (size_t)UU * DD;

    const dim3 blk(256);
    const dim3 blkA(ABLK);
    const int gridN4 = (NN + 15) / 16;    // 4 rows/wave, 4 waves/block
    const int gridU4 = (UU + 15) / 16;
    const int gridMix = (NN + 3) / 4;     // wave per row
    const int gridFin = (UU + 3) / 4;

    att_vec_kernel<<<1, 64, 0, stream>>>(uaw, uamw, iaw, iamw, saw, samw, vvec);

    // ---- build row-sorted CSR for all 7 graphs ----
    pa_count_kernel<<<GRID_A, blkA, 0, stream>>>(r_rows, f_rows, g_rows, gHistT);
    kprefix_kernel<<<(NBCK + 3) / 4, blk, 0, stream>>>(gHistT, bTot);
    bscan_kernel<<<1, blk, 0, stream>>>(bTot, bStart, rowptr);
    pa_scatter_kernel<<<GRID_A, blkA, 0, stream>>>(r_rows, r_cols, r_vals,
                                                   f_rows, f_cols, f_vals,
                                                   g_rows, g_cols, g_vals,
                                                   bStart, gHistT, ecv);
    phaseB_kernel<<<NBCK, blk, 0, stream>>>(bStart, rowptr, ecv, edata);

    // ---- rating channels ----
    for (int c = 0; c < 5; ++c) {
        spmm_kernel<0><<<gridN4, blk, 0, stream>>>(
            rowptr, c * NN, edata,
            rue + (size_t)c * UU * DD, rie + (size_t)c * II * DD, nullptr,
            nullptr, nullptr, AtmpB, nullptr, nullptr, NN);
        spmm_kernel<1><<<gridN4, blk, 0, stream>>>(
            rowptr, c * NN, edata,
            nullptr, nullptr, AtmpB, AtmpB, vvec,
            (uint2*)(chanMean + (size_t)c * NN * DD), nullptr, wrat + (size_t)c * NN, NN);
    }

    // ---- attention fuse (rating), user+item in one launch ----
    mix5_kernel<<<gridMix, blk, 0, stream>>>(chanMean, wrat, oUS, oIS, mixedRU, oMI);

    // ---- social: friend ----
    spmm_kernel<2><<<gridU4, blk, 0, stream>>>(rowptr, ROW_S0, edata, femb, nullptr, nullptr,
                                               nullptr, nullptr, socL1B, nullptr, nullptr, UU);
    spmm_kernel<3><<<gridU4, blk, 0, stream>>>(rowptr, ROW_S0, edata, nullptr, nullptr, socL1B,
                                               socL1B, nullptr, nullptr, (float4*)socM0, nullptr, UU);
    // ---- social: group ----
    spmm_kernel<2><<<gridU4, blk, 0, stream>>>(rowptr, ROW_S0 + UU, edata, gemb, nullptr, nullptr,
                                               nullptr, nullptr, socL1B, nullptr, nullptr, UU);
    spmm_kernel<3><<<gridU4, blk, 0, stream>>>(rowptr, ROW_S0 + UU, edata, nullptr, nullptr, socL1B,
                                               socL1B, nullptr, nullptr, (float4*)socM1, nullptr, UU);

    // ---- social fuse + adaptive combine ----
    social_mix_final_kernel<<<gridFin, blk, 0, stream>>>(socM0, socM1, vvec + 2 * DD,
                                                         mixedRU, adapt, oSS, oMU);
}